// Round 1
// baseline (2234.762 us; speedup 1.0000x reference)
//
#include <hip/hip_runtime.h>

// ---------------- problem constants ----------------
constexpr int NT_[4]    = {100000, 20000, 2000, 100000};   // node counts: bv, lt, cm, dn
constexpr long long NT_OFF_[4] = {0, 100000, 120000, 122000};
constexpr int ECNT_[4]  = {600000, 200000, 500000, 200000};
constexpr int ESRC_[4]  = {1, 2, 3, 0};
constexpr int EDST_[4]  = {0, 0, 1, 2};
constexpr int NDST_[4]  = {100000, 100000, 20000, 2000};
constexpr long long CSR_OFF_[4] = {0, 600000, 800000, 1300000};

// ---------------- workspace layout (byte offsets, 256-aligned) ----------------
constexpr size_t STRIDE_I   = 401408;      // 100352 ints per per-edge-type index array
constexpr size_t DEG_B      = 0;           // 4 * STRIDE_I
constexpr size_t OFF_B      = 1605632;     // 4 * STRIDE_I
constexpr size_t CUR_B      = 3211264;     // 4 * STRIDE_I
constexpr size_t CSR_B      = 4816896;     // 1.5M ints (src reordered by dst)
constexpr size_t CSRE_B     = 10817024;    // 1.5M ints (edge id reordered by dst)
constexpr size_t FTS_B      = 16817152;    // 4 * FTS_STRIDE (ft sums per dst, 16 wide)
constexpr size_t FTS_STRIDE = 6422528;
constexpr size_t Z_B        = 42507264;    // 100000*128 floats scratch (z = h_src @ W_bot)
constexpr size_t H1_B       = 93707264;    // 222000*128 floats (layer-1 hidden)
constexpr size_t WC_B       = 207371264;   // combined W_top for bv, 2 layers
constexpr size_t WS_NEEDED  = 207502336;

// ---------------- kernels ----------------

__global__ void hist_kernel(const int* __restrict__ dst, int E, int* __restrict__ deg) {
    int i = blockIdx.x * blockDim.x + threadIdx.x;
    if (i < E) atomicAdd(&deg[dst[i]], 1);
}

struct ScanArgs { int* deg[4]; int* off[4]; int* cur[4]; int N[4]; };

// one block per edge type; block scan with 16 elems/thread
__global__ void scan_kernel(ScanArgs a) {
    const int e = blockIdx.x;
    const int N = a.N[e];
    int* __restrict__ deg = a.deg[e];
    int* __restrict__ off = a.off[e];
    int* __restrict__ cur = a.cur[e];
    const int tid = threadIdx.x;
    const int lane = tid & 63, wv = tid >> 6;          // 16 waves
    __shared__ int wsum[16];
    __shared__ int chunk_total;
    int carry = 0;
    const int CHUNK = 1024 * 16;
    for (int base = 0; base < N; base += CHUNK) {
        int i0 = base + tid * 16;
        int v[16]; int s = 0;
#pragma unroll
        for (int j = 0; j < 16; j++) {
            int idx = i0 + j;
            v[j] = (idx < N) ? deg[idx] : 0;
            s += v[j];
        }
        int ssum = s;                                   // inclusive wave scan of thread sums
#pragma unroll
        for (int d = 1; d < 64; d <<= 1) {
            int t = __shfl_up(ssum, d);
            if (lane >= d) ssum += t;
        }
        if (lane == 63) wsum[wv] = ssum;
        __syncthreads();
        if (wv == 0) {                                  // exclusive scan of the 16 wave sums
            int t = (lane < 16) ? wsum[lane] : 0;
            int tt = t;
#pragma unroll
            for (int d = 1; d < 16; d <<= 1) {
                int u = __shfl_up(tt, d);
                if (lane >= d) tt += u;
            }
            if (lane < 16) wsum[lane] = tt - t;
        }
        __syncthreads();
        int run = carry + wsum[wv] + (ssum - s);        // exclusive prefix of this thread
#pragma unroll
        for (int j = 0; j < 16; j++) {
            int idx = i0 + j;
            if (idx < N) { off[idx] = run; cur[idx] = run; }
            run += v[j];
        }
        if (wv == 15 && lane == 63) chunk_total = wsum[15] + ssum;
        __syncthreads();
        carry += chunk_total;
        __syncthreads();
    }
    if (tid == 0) off[N] = carry;
}

__global__ void fill_csr_kernel(const int* __restrict__ dst, const int* __restrict__ src, int E,
                                int* __restrict__ cur, int* __restrict__ csr_src,
                                int* __restrict__ csr_eid) {
    int i = blockIdx.x * blockDim.x + threadIdx.x;
    if (i < E) {
        int p = atomicAdd(&cur[dst[i]], 1);
        csr_src[p] = src[i];
        csr_eid[p] = i;
    }
}

// per-dst sum of ft rows (16-wide); one wave per dst node, 4 edges in flight
__global__ void ft_pull_kernel(const float* __restrict__ ft, const int* __restrict__ eid,
                               const int* __restrict__ off, float* __restrict__ ftsum, int N) {
    int wid = (blockIdx.x * blockDim.x + threadIdx.x) >> 6;
    int lane = threadIdx.x & 63;
    if (wid >= N) return;
    int s = off[wid], e = off[wid + 1];
    int sub = lane >> 4;       // 0..3
    int k = lane & 15;
    float acc = 0.f;
    for (int j = s + sub; j < e; j += 4) acc += ft[(long long)eid[j] * 16 + k];
    acc += __shfl_down(acc, 32);
    acc += __shfl_down(acc, 16);
    if (lane < 16) ftsum[(long long)wid * 16 + k] = acc;
}

__global__ void combine_w_kernel(const float* __restrict__ convW, float* __restrict__ wcomb) {
    int i = blockIdx.x * blockDim.x + threadIdx.x;   // 2*16384
    if (i < 2 * 128 * 128) {
        int l = i / 16384, r = i % 16384;
        wcomb[i] = convW[(size_t)(l * 4 + 0) * 32768 + r] + convW[(size_t)(l * 4 + 1) * 32768 + r];
    }
}

// out[n,d] = sum over incoming edge types of (conv_b + (deg>0 ? mean(ft)@emlpW + emlpb : 0))
__global__ void init_out_kernel(float* __restrict__ out, int N,
        const int* __restrict__ deg0, const float* __restrict__ fts0,
        const float* __restrict__ eW0, const float* __restrict__ eb0, const float* __restrict__ cb0,
        const int* __restrict__ deg1, const float* __restrict__ fts1,
        const float* __restrict__ eW1, const float* __restrict__ eb1, const float* __restrict__ cb1) {
    long long i = (long long)blockIdx.x * blockDim.x + threadIdx.x;
    if (i >= (long long)N * 128) return;
    int n = (int)(i >> 7), d = (int)(i & 127);
    float acc = cb0[d];
    if (cb1) acc += cb1[d];
    int dg = deg0[n];
    if (dg > 0) {
        float inv = 1.f / (float)dg;
        float s = eb0[d];
#pragma unroll
        for (int k = 0; k < 16; k++) s += fts0[(long long)n * 16 + k] * inv * eW0[k * 128 + d];
        acc += s;
    }
    if (deg1) {
        dg = deg1[n];
        if (dg > 0) {
            float inv = 1.f / (float)dg;
            float s = eb1[d];
#pragma unroll
            for (int k = 0; k < 16; k++) s += fts1[(long long)n * 16 + k] * inv * eW1[k * 128 + d];
            acc += s;
        }
    }
    out[i] = acc;
}

// C[M,128] = (acc ? C : 0) + A[M,128] @ W[128,128]; BM=128, 8x8 register tile
__global__ __launch_bounds__(256) void gemm128_kernel(
        float* __restrict__ C, const float* __restrict__ A, const float* __restrict__ W,
        int M, int accumulate) {
    __shared__ float AsT[128][132];   // [k][row], padded
    __shared__ float Ws[128][128];    // [k][col]
    const int tid = threadIdx.x;
    const long long row0 = (long long)blockIdx.x * 128;

#pragma unroll
    for (int i = 0; i < 16; i++) {
        int idx = tid + i * 256;             // 0..4095
        int k = idx >> 5;
        int c4 = (idx & 31) << 2;
        *(float4*)&Ws[k][c4] = *(const float4*)&W[k * 128 + c4];
    }
#pragma unroll
    for (int i = 0; i < 16; i++) {
        int idx = tid + i * 256;
        int r = idx >> 5;
        int k4 = (idx & 31) << 2;
        long long gr = row0 + r;
        float4 v = make_float4(0.f, 0.f, 0.f, 0.f);
        if (gr < M) v = *(const float4*)&A[gr * 128 + k4];
        AsT[k4 + 0][r] = v.x;
        AsT[k4 + 1][r] = v.y;
        AsT[k4 + 2][r] = v.z;
        AsT[k4 + 3][r] = v.w;
    }
    __syncthreads();

    const int tr = tid >> 4;   // 0..15  (rows tr*8..tr*8+7)
    const int tc = tid & 15;   // 0..15  (cols tc*8..tc*8+7)
    float acc[8][8];
#pragma unroll
    for (int i = 0; i < 8; i++)
#pragma unroll
        for (int j = 0; j < 8; j++) acc[i][j] = 0.f;

#pragma unroll 4
    for (int k = 0; k < 128; k++) {
        float a[8], w[8];
        *(float4*)&a[0] = *(const float4*)&AsT[k][tr * 8];
        *(float4*)&a[4] = *(const float4*)&AsT[k][tr * 8 + 4];
        *(float4*)&w[0] = *(const float4*)&Ws[k][tc * 8];
        *(float4*)&w[4] = *(const float4*)&Ws[k][tc * 8 + 4];
#pragma unroll
        for (int i = 0; i < 8; i++)
#pragma unroll
            for (int j = 0; j < 8; j++) acc[i][j] += a[i] * w[j];
    }

#pragma unroll
    for (int i = 0; i < 8; i++) {
        long long gr = row0 + tr * 8 + i;
        if (gr < M) {
            float* cp = &C[gr * 128 + tc * 8];
            if (accumulate) {
                float4 c0 = *(float4*)&cp[0], c1 = *(float4*)&cp[4];
                c0.x += acc[i][0]; c0.y += acc[i][1]; c0.z += acc[i][2]; c0.w += acc[i][3];
                c1.x += acc[i][4]; c1.y += acc[i][5]; c1.z += acc[i][6]; c1.w += acc[i][7];
                *(float4*)&cp[0] = c0; *(float4*)&cp[4] = c1;
            } else {
                *(float4*)&cp[0] = make_float4(acc[i][0], acc[i][1], acc[i][2], acc[i][3]);
                *(float4*)&cp[4] = make_float4(acc[i][4], acc[i][5], acc[i][6], acc[i][7]);
            }
        }
    }
}

// out[n,:] += (1/deg) * sum_{j in CSR(n)} z[csr_src[j], :]; one wave per dst row
__global__ void agg_pull_kernel(const float* __restrict__ z, const int* __restrict__ csr,
                                const int* __restrict__ off, float* __restrict__ out, int N) {
    int wid = (blockIdx.x * blockDim.x + threadIdx.x) >> 6;
    int lane = threadIdx.x & 63;
    if (wid >= N) return;
    int s = off[wid], e = off[wid + 1];
    if (s == e) return;
    float2 acc = make_float2(0.f, 0.f);
    for (int j = s; j < e; j++) {
        int sr = csr[j];
        float2 v = *(const float2*)&z[(long long)sr * 128 + lane * 2];
        acc.x += v.x; acc.y += v.y;
    }
    float inv = 1.f / (float)(e - s);
    float2* o = (float2*)&out[(long long)wid * 128 + lane * 2];
    float2 c = *o;
    c.x += acc.x * inv; c.y += acc.y * inv;
    *o = c;
}

// in-place LayerNorm; one wave per row (2 elems per lane)
__global__ void ln_kernel(float* __restrict__ x, const float* __restrict__ g,
                          const float* __restrict__ b, int N) {
    int wid = (blockIdx.x * blockDim.x + threadIdx.x) >> 6;
    int lane = threadIdx.x & 63;
    if (wid >= N) return;
    float2 v = *(float2*)&x[(long long)wid * 128 + lane * 2];
    float s = v.x + v.y;
    float s2 = v.x * v.x + v.y * v.y;
#pragma unroll
    for (int o = 32; o > 0; o >>= 1) {
        s += __shfl_down(s, o);
        s2 += __shfl_down(s2, o);
    }
    s = __shfl(s, 0); s2 = __shfl(s2, 0);
    float m = s * (1.f / 128.f);
    float var = s2 * (1.f / 128.f) - m * m;
    float r = rsqrtf(var + 1e-5f);
    v.x = (v.x - m) * r * g[lane * 2 + 0] + b[lane * 2 + 0];
    v.y = (v.y - m) * r * g[lane * 2 + 1] + b[lane * 2 + 1];
    *(float2*)&x[(long long)wid * 128 + lane * 2] = v;
}

__global__ void fill_dn_kernel(float* __restrict__ out, const float* __restrict__ b, long long n) {
    long long i = (long long)blockIdx.x * blockDim.x + threadIdx.x;
    if (i < n) out[i] = b[i & 127];
}

// ---------------- host launch ----------------
extern "C" void kernel_launch(void* const* d_in, const int* in_sizes, int n_in,
                              void* d_out, int out_size, void* d_ws, size_t ws_size,
                              hipStream_t stream) {
    if (ws_size < WS_NEEDED) return;  // workspace too small; fail loudly via wrong output

    const float* h0[4] = {(const float*)d_in[0], (const float*)d_in[1],
                          (const float*)d_in[2], (const float*)d_in[3]};
    const float* ft[4] = {(const float*)d_in[4], (const float*)d_in[5],
                          (const float*)d_in[6], (const float*)d_in[7]};
    const float* convW = (const float*)d_in[8];
    const float* convb = (const float*)d_in[9];
    const float* emlpW = (const float*)d_in[10];
    const float* emlpb = (const float*)d_in[11];
    const float* lng   = (const float*)d_in[12];
    const float* lnb   = (const float*)d_in[13];
    const int* src[4] = {(const int*)d_in[14], (const int*)d_in[16],
                         (const int*)d_in[18], (const int*)d_in[20]};
    const int* dst[4] = {(const int*)d_in[15], (const int*)d_in[17],
                         (const int*)d_in[19], (const int*)d_in[21]};
    char* ws = (char*)d_ws;
    float* out = (float*)d_out;

    int* degp[4]; int* offp[4]; int* curp[4]; int* csrp[4]; int* eidp[4]; float* ftsp[4];
    for (int e = 0; e < 4; e++) {
        degp[e] = (int*)(ws + DEG_B + (size_t)e * STRIDE_I);
        offp[e] = (int*)(ws + OFF_B + (size_t)e * STRIDE_I);
        curp[e] = (int*)(ws + CUR_B + (size_t)e * STRIDE_I);
        csrp[e] = (int*)(ws + CSR_B) + CSR_OFF_[e];
        eidp[e] = (int*)(ws + CSRE_B) + CSR_OFF_[e];
        ftsp[e] = (float*)(ws + FTS_B + (size_t)e * FTS_STRIDE);
    }
    float* z     = (float*)(ws + Z_B);
    float* h1    = (float*)(ws + H1_B);
    float* wcomb = (float*)(ws + WC_B);

    // ---- setup (per call; indices are constant but we must redo identical work) ----
    hipMemsetAsync(ws + DEG_B, 0, 4 * STRIDE_I, stream);
    for (int e = 0; e < 4; e++)
        hist_kernel<<<(ECNT_[e] + 255) / 256, 256, 0, stream>>>(dst[e], ECNT_[e], degp[e]);

    ScanArgs sa;
    for (int e = 0; e < 4; e++) { sa.deg[e] = degp[e]; sa.off[e] = offp[e]; sa.cur[e] = curp[e]; sa.N[e] = NDST_[e]; }
    scan_kernel<<<4, 1024, 0, stream>>>(sa);

    for (int e = 0; e < 4; e++)
        fill_csr_kernel<<<(ECNT_[e] + 255) / 256, 256, 0, stream>>>(dst[e], src[e], ECNT_[e],
                                                                    curp[e], csrp[e], eidp[e]);
    for (int e = 0; e < 4; e++)
        ft_pull_kernel<<<(NDST_[e] + 3) / 4, 256, 0, stream>>>(ft[e], eidp[e], offp[e], ftsp[e], NDST_[e]);

    combine_w_kernel<<<128, 256, 0, stream>>>(convW, wcomb);

    // ---- layers ----
    for (int l = 0; l < 2; l++) {
        const float* hin[4]; float* hout[4];
        for (int t = 0; t < 4; t++) {
            hin[t]  = (l == 0) ? h0[t] : (h1 + NT_OFF_[t] * 128);
            hout[t] = (l == 0) ? (h1 + NT_OFF_[t] * 128) : (out + NT_OFF_[t] * 128);
        }
        // bias init (conv_b + gated edge-MLP mean) per receiving node type
        init_out_kernel<<<(100000 * 128 + 255) / 256, 256, 0, stream>>>(hout[0], 100000,
            degp[0], ftsp[0], emlpW + 0 * 2048, emlpb + 0 * 128, convb + (l * 4 + 0) * 128,
            degp[1], ftsp[1], emlpW + 1 * 2048, emlpb + 1 * 128, convb + (l * 4 + 1) * 128);
        init_out_kernel<<<(20000 * 128 + 255) / 256, 256, 0, stream>>>(hout[1], 20000,
            degp[2], ftsp[2], emlpW + 2 * 2048, emlpb + 2 * 128, convb + (l * 4 + 2) * 128,
            nullptr, nullptr, nullptr, nullptr, nullptr);
        init_out_kernel<<<(2000 * 128 + 255) / 256, 256, 0, stream>>>(hout[2], 2000,
            degp[3], ftsp[3], emlpW + 3 * 2048, emlpb + 3 * 128, convb + (l * 4 + 3) * 128,
            nullptr, nullptr, nullptr, nullptr, nullptr);

        // per edge type: z = h_src @ W_bot, then pull-aggregate into out
        for (int e = 0; e < 4; e++) {
            int si = ESRC_[e], di = EDST_[e];
            int Ms = NT_[si];
            const float* Wbot = convW + ((size_t)(l * 4 + e) * 256 + 128) * 128;
            gemm128_kernel<<<(Ms + 127) / 128, 256, 0, stream>>>(z, hin[si], Wbot, Ms, 0);
            agg_pull_kernel<<<(NDST_[e] + 3) / 4, 256, 0, stream>>>(z, csrp[e], offp[e], hout[di], NDST_[e]);
        }

        // self term: out += h_dst @ W_top (bv uses combined e0+e1 W_top)
        gemm128_kernel<<<(100000 + 127) / 128, 256, 0, stream>>>(hout[0], hin[0], wcomb + (size_t)l * 16384, 100000, 1);
        gemm128_kernel<<<(20000 + 127) / 128, 256, 0, stream>>>(hout[1], hin[1], convW + ((size_t)(l * 4 + 2) * 256) * 128, 20000, 1);
        gemm128_kernel<<<(2000 + 127) / 128, 256, 0, stream>>>(hout[2], hin[2], convW + ((size_t)(l * 4 + 3) * 256) * 128, 2000, 1);

        // LayerNorm (in place); donor output is exactly ln_b[3]
        ln_kernel<<<(100000 + 3) / 4, 256, 0, stream>>>(hout[0], lng + 0,   lnb + 0,   100000);
        ln_kernel<<<(20000 + 3) / 4, 256, 0, stream>>>(hout[1], lng + 128, lnb + 128, 20000);
        ln_kernel<<<(2000 + 3) / 4, 256, 0, stream>>>(hout[2], lng + 256, lnb + 256, 2000);
        fill_dn_kernel<<<(100000 * 128 + 255) / 256, 256, 0, stream>>>(hout[3], lnb + 384, (long long)100000 * 128);
    }
}

// Round 2
// 1509.929 us; speedup vs baseline: 1.4800x; 1.4800x over previous
//
#include <hip/hip_runtime.h>

typedef short v8s __attribute__((ext_vector_type(8)));
typedef float v4f __attribute__((ext_vector_type(4)));

#define S_I 100352

// ---------------- workspace byte offsets (256-aligned) ----------------
#define DEG_B   0ull
#define OFF_B   1605632ull
#define CUR_B   3211264ull
#define CSRS_B  4816896ull
#define CSRE_B  10817024ull
#define FTS_B   16817152ull
#define BSUM_B  31025408ull
#define BPRE_B  31041792ull
#define WT_B    31058176ull
#define HA_B    31516928ull
#define ZA_B    88349184ull
#define HO_B    145181440ull
#define WS_NEEDED 176413440ull

__device__ __forceinline__ unsigned short f2bf(float f) {
    unsigned u = __float_as_uint(f);
    u += 0x7fffu + ((u >> 16) & 1u);
    return (unsigned short)(u >> 16);
}
__device__ __forceinline__ float bf2f(unsigned short h) {
    return __uint_as_float(((unsigned)h) << 16);
}

struct IPtr4 { const int* p[4]; };
struct IPtr8 { const int* s[4]; const int* d[4]; };
struct FPtr4 { const float* p[4]; };

// ---------------- setup kernels ----------------

__global__ void hist_all(IPtr4 dst, int* __restrict__ deg) {
    int i = blockIdx.x * 256 + threadIdx.x;
    if (i >= 1500000) return;
    int e, li;
    if (i < 600000)       { e = 0; li = i; }
    else if (i < 800000)  { e = 1; li = i - 600000; }
    else if (i < 1300000) { e = 2; li = i - 800000; }
    else                  { e = 3; li = i - 1300000; }
    atomicAdd(&deg[e * S_I + dst.p[e][li]], 1);
}

__device__ __forceinline__ void blk_decode(int b, int& e, int& lb, int& N) {
    if (b < 98)       { e = 0; lb = b;       N = 100000; }
    else if (b < 196) { e = 1; lb = b - 98;  N = 100000; }
    else if (b < 216) { e = 2; lb = b - 196; N = 20000;  }
    else              { e = 3; lb = b - 216; N = 2000;   }
}

__global__ void scan_p1(const int* __restrict__ deg, int* __restrict__ bsum) {
    int tid = threadIdx.x;
    int e, lb, N;
    blk_decode(blockIdx.x, e, lb, N);
    const int* dg = deg + e * S_I;
    int base = lb * 1024 + tid * 4;
    int s = 0;
#pragma unroll
    for (int j = 0; j < 4; j++) { int i = base + j; if (i < N) s += dg[i]; }
    for (int o = 32; o > 0; o >>= 1) s += __shfl_down(s, o);
    __shared__ int wsm[4];
    if ((tid & 63) == 0) wsm[tid >> 6] = s;
    __syncthreads();
    if (tid == 0) bsum[e * 512 + lb] = wsm[0] + wsm[1] + wsm[2] + wsm[3];
}

__global__ void scan_p2(const int* __restrict__ bsum, int* __restrict__ bpre, int* __restrict__ off) {
    __shared__ int sh[256];
    int tid = threadIdx.x;
    for (int e = 0; e < 4; e++) {
        int nb = (e < 2) ? 98 : (e == 2 ? 20 : 2);
        int N  = (e < 2) ? 100000 : (e == 2 ? 20000 : 2000);
        int v = (tid < nb) ? bsum[e * 512 + tid] : 0;
        sh[tid] = v;
        __syncthreads();
        for (int s = 1; s < 256; s <<= 1) {
            int t = (tid >= s) ? sh[tid - s] : 0;
            __syncthreads();
            sh[tid] += t;
            __syncthreads();
        }
        if (tid < nb) bpre[e * 512 + tid] = sh[tid] - v;
        if (tid == 0) off[e * S_I + N] = sh[255];
        __syncthreads();
    }
}

__global__ void scan_p3(const int* __restrict__ deg, const int* __restrict__ bpre,
                        int* __restrict__ off, int* __restrict__ cur) {
    int tid = threadIdx.x;
    int e, lb, N;
    blk_decode(blockIdx.x, e, lb, N);
    const int* dg = deg + e * S_I;
    int base = lb * 1024 + tid * 4;
    int v[4], s = 0;
#pragma unroll
    for (int j = 0; j < 4; j++) { int i = base + j; v[j] = (i < N) ? dg[i] : 0; s += v[j]; }
    int lane = tid & 63, w = tid >> 6;
    int sc = s;
    for (int d = 1; d < 64; d <<= 1) { int t = __shfl_up(sc, d); if (lane >= d) sc += t; }
    __shared__ int wsm[4];
    if (lane == 63) wsm[w] = sc;
    __syncthreads();
    int wpre = 0;
    for (int ww = 0; ww < 4; ww++) if (ww < w) wpre += wsm[ww];
    int run = bpre[e * 512 + lb] + wpre + (sc - s);
#pragma unroll
    for (int j = 0; j < 4; j++) {
        int i = base + j;
        if (i < N) { off[e * S_I + i] = run; cur[e * S_I + i] = run; }
        run += v[j];
    }
}

__global__ void fillcsr_all(IPtr8 sd, int* __restrict__ cur,
                            int* __restrict__ csr_src, int* __restrict__ csr_eid) {
    int i = blockIdx.x * 256 + threadIdx.x;
    if (i >= 1500000) return;
    int e, li, eo;
    if (i < 600000)       { e = 0; li = i;           eo = 0; }
    else if (i < 800000)  { e = 1; li = i - 600000;  eo = 600000; }
    else if (i < 1300000) { e = 2; li = i - 800000;  eo = 800000; }
    else                  { e = 3; li = i - 1300000; eo = 1300000; }
    int d = sd.d[e][li];
    int p = atomicAdd(&cur[e * S_I + d], 1);
    csr_src[eo + p] = sd.s[e][li];
    csr_eid[eo + p] = li;
}

// per-(etype,dst) sum of ft rows (16-wide); one wave per dst node
__global__ void ftpull_all(FPtr4 ft, const int* __restrict__ csr_eid,
                           const int* __restrict__ off, float* __restrict__ fts) {
    int gid = blockIdx.x * 256 + threadIdx.x;
    int wid = gid >> 6, lane = gid & 63;
    if (wid >= 222000) return;
    int e, n, eo;
    if (wid < 100000)      { e = 0; n = wid;          eo = 0; }
    else if (wid < 200000) { e = 1; n = wid - 100000; eo = 600000; }
    else if (wid < 220000) { e = 2; n = wid - 200000; eo = 800000; }
    else                   { e = 3; n = wid - 220000; eo = 1300000; }
    int s = off[e * S_I + n], t = off[e * S_I + n + 1];
    int sub = lane >> 4, k = lane & 15;
    const float* fp = ft.p[e];
    float a = 0.f;
    for (int j = s + sub; j < t; j += 4) a += fp[(long long)csr_eid[eo + j] * 16 + k];
    a += __shfl_down(a, 32);
    a += __shfl_down(a, 16);
    if (lane < 16) fts[(long long)wid * 16 + k] = a;
}

// build bf16 W^T tiles: slots 0-3 = W_bot(e)^T, 4 = (W_top0+W_top1)^T, 5 = W_top2^T, 6 = W_top3^T
__global__ void wprep(const float* __restrict__ convW, unsigned short* __restrict__ wt) {
    int i = blockIdx.x * 256 + threadIdx.x;
    if (i >= 229376) return;
    int l = i / 114688;
    int rem = i - l * 114688;
    int slot = rem >> 14;
    int idx = rem & 16383;
    int c = idx >> 7, k = idx & 127;
    float v;
    if (slot < 4)
        v = convW[((size_t)(l * 4 + slot) * 256 + 128 + k) * 128 + c];
    else if (slot == 4)
        v = convW[((size_t)(l * 4 + 0) * 256 + k) * 128 + c] +
            convW[((size_t)(l * 4 + 1) * 256 + k) * 128 + c];
    else
        v = convW[((size_t)(l * 4 + (slot - 3)) * 256 + k) * 128 + c];
    wt[i] = f2bf(v);
}

__global__ void h0cvt(FPtr4 h, unsigned short* __restrict__ ha) {
    long long i4 = ((long long)blockIdx.x * 256 + threadIdx.x) * 4;
    if (i4 >= 28416000ll) return;
    long long r = i4 >> 7;
    int c = (int)(i4 & 127);
    int t; long long lr;
    if (r < 100000)      { t = 0; lr = r; }
    else if (r < 120000) { t = 1; lr = r - 100000; }
    else if (r < 122000) { t = 2; lr = r - 120000; }
    else                 { t = 3; lr = r - 122000; }
    const float4 v = *(const float4*)&h.p[t][lr * 128 + c];
    ushort4 o;
    o.x = f2bf(v.x); o.y = f2bf(v.y); o.z = f2bf(v.z); o.w = f2bf(v.w);
    *(ushort4*)&ha[i4] = o;
}

// ---------------- fused bias + aggregation pull (writes hout bf16) ----------------
// hout[n,:] = sum over incoming e of (conv_b[l,e] + gate*(mean ft @ emlpW + emlpb) + mean_z)
__global__ void pull_all(int l, const int* __restrict__ off, const int* __restrict__ csr_src,
                         const unsigned short* __restrict__ za, const float* __restrict__ fts,
                         const float* __restrict__ convb, const float* __restrict__ emlpW,
                         const float* __restrict__ emlpb, unsigned short* __restrict__ hout) {
    long long gid = (long long)blockIdx.x * 256 + threadIdx.x;
    int wid = (int)(gid >> 6), lane = (int)(gid & 63);
    if (wid >= 122000) return;
    int t, n;
    if (wid < 100000)      { t = 0; n = wid; }
    else if (wid < 120000) { t = 1; n = wid - 100000; }
    else                   { t = 2; n = wid - 120000; }
    int c0 = lane * 2;
    int efirst = (t == 0) ? 0 : (t == 1) ? 2 : 3;
    int ne = (t == 0) ? 2 : 1;
    float a0 = 0.f, a1 = 0.f;
    for (int ii = 0; ii < ne; ii++) {
        int e = efirst + ii;
        a0 += convb[(l * 4 + e) * 128 + c0];
        a1 += convb[(l * 4 + e) * 128 + c0 + 1];
        int s = off[e * S_I + n], en = off[e * S_I + n + 1];
        int cnt = en - s;
        if (cnt > 0) {
            float inv = 1.f / (float)cnt;
            int ftrow = ((e == 0) ? 0 : (e == 1) ? 100000 : (e == 2) ? 200000 : 220000) + n;
            const float* fr = fts + (long long)ftrow * 16;
            float s0 = emlpb[e * 128 + c0], s1 = emlpb[e * 128 + c0 + 1];
#pragma unroll
            for (int k = 0; k < 16; k++) {
                float f = fr[k] * inv;
                s0 += f * emlpW[e * 2048 + k * 128 + c0];
                s1 += f * emlpW[e * 2048 + k * 128 + c0 + 1];
            }
            int eo = (e == 0) ? 0 : (e == 1) ? 600000 : (e == 2) ? 800000 : 1300000;
            long long zoff = (e == 0) ? 0 : (e == 1) ? 20000 : (e == 2) ? 22000 : 122000;
            const int* cs = csr_src + eo + s;
            const unsigned short* zb = za + zoff * 128;
            float g0 = 0.f, g1 = 0.f;
            for (int j = 0; j < cnt; j++) {
                int sr = cs[j];
                unsigned v = *(const unsigned*)&zb[(long long)sr * 128 + c0];
                g0 += __uint_as_float(v << 16);
                g1 += __uint_as_float(v & 0xffff0000u);
            }
            a0 += s0 + g0 * inv;
            a1 += s1 + g1 * inv;
        }
    }
    unsigned pack = (unsigned)f2bf(a0) | ((unsigned)f2bf(a1) << 16);
    *(unsigned*)&hout[(long long)wid * 128 + c0] = pack;
}

// ---------------- MFMA GEMM: C[M,128] = A[M,128] @ W[128,128] ----------------
// mode 0: store z (bf16).  mode 1: +Cadd, LayerNorm, store bf16 (h1).
// mode 2: +Cadd, LayerNorm, store fp32 (final out).
// LDS XOR-swizzle: 16B chunk c of row m stored at chunk (c ^ (m&15)).
__global__ __launch_bounds__(256, 2) void gemm_mfma(
    const unsigned short* A, const unsigned short* __restrict__ Wt,
    int M, int mode,
    unsigned short* outb, float* __restrict__ outf,
    const unsigned short* __restrict__ Cadd,
    const float* __restrict__ g, const float* __restrict__ bb) {
    __shared__ unsigned short As[16384];
    __shared__ unsigned short Bs[16384];
    int tid = threadIdx.x;
    long long row0 = (long long)blockIdx.x * 128;
#pragma unroll
    for (int i = 0; i < 8; i++) {
        int idx = tid + i * 256;
        int m = idx >> 4, c = idx & 15;
        int sw = c ^ (m & 15);
        uint4 v = make_uint4(0u, 0u, 0u, 0u);
        long long gr = row0 + m;
        if (gr < M) v = *(const uint4*)&A[gr * 128 + c * 8];
        *(uint4*)&As[m * 128 + sw * 8] = v;
        uint4 wv = *(const uint4*)&Wt[m * 128 + c * 8];
        *(uint4*)&Bs[m * 128 + sw * 8] = wv;
    }
    __syncthreads();
    int lane = tid & 63, w = tid >> 6;
    int q = lane >> 4, ml = lane & 15;
    v4f acc[2][8];
#pragma unroll
    for (int i = 0; i < 2; i++)
#pragma unroll
        for (int j = 0; j < 8; j++) acc[i][j] = (v4f){0.f, 0.f, 0.f, 0.f};
#pragma unroll
    for (int kc = 0; kc < 4; kc++) {
        int ch = (4 * kc + q) ^ ml;
        v8s af[2], bf[8];
#pragma unroll
        for (int i = 0; i < 2; i++) {
            int m = 32 * w + 16 * i + ml;
            af[i] = *(const v8s*)&As[m * 128 + ch * 8];
        }
#pragma unroll
        for (int j = 0; j < 8; j++) {
            int cc = 16 * j + ml;
            bf[j] = *(const v8s*)&Bs[cc * 128 + ch * 8];
        }
#pragma unroll
        for (int i = 0; i < 2; i++)
#pragma unroll
            for (int j = 0; j < 8; j++)
                acc[i][j] = __builtin_amdgcn_mfma_f32_16x16x32_bf16(af[i], bf[j], acc[i][j], 0, 0, 0);
    }
    if (mode == 0) {
#pragma unroll
        for (int i = 0; i < 2; i++)
#pragma unroll
            for (int r = 0; r < 4; r++) {
                long long row = row0 + 32 * w + 16 * i + q * 4 + r;
                if (row < M) {
#pragma unroll
                    for (int j = 0; j < 8; j++)
                        outb[row * 128 + 16 * j + ml] = f2bf(acc[i][j][r]);
                }
            }
        return;
    }
    float gv[8], bv[8];
#pragma unroll
    for (int j = 0; j < 8; j++) { gv[j] = g[16 * j + ml]; bv[j] = bb[16 * j + ml]; }
#pragma unroll
    for (int i = 0; i < 2; i++) {
#pragma unroll
        for (int r = 0; r < 4; r++) {
            long long row = row0 + 32 * w + 16 * i + q * 4 + r;
            bool valid = row < M;
            float s = 0.f, s2 = 0.f;
#pragma unroll
            for (int j = 0; j < 8; j++) {
                float v = acc[i][j][r];
                if (valid) v += bf2f(Cadd[row * 128 + 16 * j + ml]);
                acc[i][j][r] = v;
                s += v; s2 += v * v;
            }
#pragma unroll
            for (int msk = 1; msk < 16; msk <<= 1) {
                s  += __shfl_xor(s,  msk);
                s2 += __shfl_xor(s2, msk);
            }
            float mean = s * 0.0078125f;
            float var  = s2 * 0.0078125f - mean * mean;
            float rs = rsqrtf(var + 1e-5f);
            if (valid) {
#pragma unroll
                for (int j = 0; j < 8; j++) {
                    float v = (acc[i][j][r] - mean) * rs * gv[j] + bv[j];
                    if (mode == 1) outb[row * 128 + 16 * j + ml] = f2bf(v);
                    else           outf[row * 128 + 16 * j + ml] = v;
                }
            }
        }
    }
}

// donor nodes receive no edges: output is exactly ln_b[3] broadcast
__global__ void fill_dn(unsigned short* __restrict__ ob, float* __restrict__ of,
                        const float* __restrict__ lnb3, int bfmode) {
    long long i4 = ((long long)blockIdx.x * 256 + threadIdx.x) * 4;
    if (i4 >= 12800000ll) return;
    int c = (int)(i4 & 127);
    float x = lnb3[c], y = lnb3[c + 1], z = lnb3[c + 2], w = lnb3[c + 3];
    if (bfmode) {
        ushort4 o; o.x = f2bf(x); o.y = f2bf(y); o.z = f2bf(z); o.w = f2bf(w);
        *(ushort4*)&ob[i4] = o;
    } else {
        *(float4*)&of[i4] = make_float4(x, y, z, w);
    }
}

// ---------------- host launch ----------------
extern "C" void kernel_launch(void* const* d_in, const int* in_sizes, int n_in,
                              void* d_out, int out_size, void* d_ws, size_t ws_size,
                              hipStream_t stream) {
    if (ws_size < WS_NEEDED) return;

    const float* h0[4] = {(const float*)d_in[0], (const float*)d_in[1],
                          (const float*)d_in[2], (const float*)d_in[3]};
    const float* ftp[4] = {(const float*)d_in[4], (const float*)d_in[5],
                           (const float*)d_in[6], (const float*)d_in[7]};
    const float* convW = (const float*)d_in[8];
    const float* convb = (const float*)d_in[9];
    const float* emlpW = (const float*)d_in[10];
    const float* emlpb = (const float*)d_in[11];
    const float* lng   = (const float*)d_in[12];
    const float* lnb   = (const float*)d_in[13];
    const int* srcp[4] = {(const int*)d_in[14], (const int*)d_in[16],
                          (const int*)d_in[18], (const int*)d_in[20]};
    const int* dstp[4] = {(const int*)d_in[15], (const int*)d_in[17],
                          (const int*)d_in[19], (const int*)d_in[21]};
    char* ws = (char*)d_ws;
    float* out = (float*)d_out;

    int* deg = (int*)(ws + DEG_B);
    int* off = (int*)(ws + OFF_B);
    int* cur = (int*)(ws + CUR_B);
    int* csr_src = (int*)(ws + CSRS_B);
    int* csr_eid = (int*)(ws + CSRE_B);
    float* fts = (float*)(ws + FTS_B);
    int* bsum = (int*)(ws + BSUM_B);
    int* bpre = (int*)(ws + BPRE_B);
    unsigned short* wt = (unsigned short*)(ws + WT_B);
    unsigned short* ha = (unsigned short*)(ws + HA_B);
    unsigned short* za = (unsigned short*)(ws + ZA_B);
    unsigned short* ho = (unsigned short*)(ws + HO_B);

    hipMemsetAsync(deg, 0, 4 * S_I * sizeof(int), stream);
    IPtr4 dsts; for (int e = 0; e < 4; e++) dsts.p[e] = dstp[e];
    hist_all<<<5860, 256, 0, stream>>>(dsts, deg);
    scan_p1<<<218, 256, 0, stream>>>(deg, bsum);
    scan_p2<<<1, 256, 0, stream>>>(bsum, bpre, off);
    scan_p3<<<218, 256, 0, stream>>>(deg, bpre, off, cur);
    IPtr8 sd;
    for (int e = 0; e < 4; e++) { sd.s[e] = srcp[e]; sd.d[e] = dstp[e]; }
    fillcsr_all<<<5860, 256, 0, stream>>>(sd, cur, csr_src, csr_eid);
    FPtr4 ftq; for (int e = 0; e < 4; e++) ftq.p[e] = ftp[e];
    ftpull_all<<<55500, 256, 0, stream>>>(ftq, csr_eid, off, fts);
    wprep<<<896, 256, 0, stream>>>(convW, wt);
    FPtr4 hq; for (int t = 0; t < 4; t++) hq.p[t] = h0[t];
    h0cvt<<<27750, 256, 0, stream>>>(hq, ha);

    const long long NTOFF[4] = {0, 100000, 120000, 122000};
    const int NTn[4] = {100000, 20000, 2000, 100000};
    const int esrc[4] = {1, 2, 3, 0};
    const long long zoffr[4] = {0, 20000, 22000, 122000};

    for (int l = 0; l < 2; l++) {
        // z_e = h_src @ W_bot(e)  (bf16 out)
        for (int e = 0; e < 4; e++) {
            int si = esrc[e], Ms = NTn[si];
            gemm_mfma<<<(Ms + 127) / 128, 256, 0, stream>>>(
                ha + NTOFF[si] * 128, wt + (size_t)(l * 7 + e) * 16384, Ms, 0,
                za + zoffr[e] * 128, nullptr, nullptr, nullptr, nullptr);
        }
        // bias + aggregation means -> hout (bf16)
        pull_all<<<30500, 256, 0, stream>>>(l, off, csr_src, za, fts, convb, emlpW, emlpb, ho);
        // self-term + accumulate + LayerNorm
        for (int t = 0; t < 3; t++) {
            int Ms = NTn[t];
            int slot = 4 + t;
            long long hooff = (t == 0) ? 0 : (t == 1) ? 100000 : 120000;
            if (l == 0)
                gemm_mfma<<<(Ms + 127) / 128, 256, 0, stream>>>(
                    ha + NTOFF[t] * 128, wt + (size_t)(l * 7 + slot) * 16384, Ms, 1,
                    ha + NTOFF[t] * 128, nullptr, ho + hooff * 128,
                    lng + t * 128, lnb + t * 128);
            else
                gemm_mfma<<<(Ms + 127) / 128, 256, 0, stream>>>(
                    ha + NTOFF[t] * 128, wt + (size_t)(l * 7 + slot) * 16384, Ms, 2,
                    nullptr, out + NTOFF[t] * 128, ho + hooff * 128,
                    lng + t * 128, lnb + t * 128);
        }
        if (l == 0)
            fill_dn<<<12500, 256, 0, stream>>>(ha + NTOFF[3] * 128, nullptr, lnb + 384, 1);
        else
            fill_dn<<<12500, 256, 0, stream>>>(nullptr, out + NTOFF[3] * 128, lnb + 384, 0);
    }
}

// Round 3
// 904.645 us; speedup vs baseline: 2.4703x; 1.6691x over previous
//
#include <hip/hip_runtime.h>

typedef short v8s __attribute__((ext_vector_type(8)));
typedef float v4f __attribute__((ext_vector_type(4)));

#define S_I 100352

// ---------------- workspace byte offsets (256-aligned) ----------------
#define DEG_B   0ull
#define OFF_B   1605632ull
#define CUR_B   3211264ull
#define CSRS_B  4816896ull
#define CSRE_B  10817024ull
#define FTS_B   16817152ull
#define BSUM_B  31025152ull
#define BPRE_B  31033344ull
#define WT_B    31041536ull
#define WEXT_B  31500288ull
#define VROW_B  31598592ull
#define AEXT_B  31599104ull
#define HA_B    47215104ull
#define ZA_B    104047104ull
#define HO_B    160879104ull
#define WS_NEEDED 192111104ull

__device__ __forceinline__ unsigned short f2bf(float f) {
    unsigned u = __float_as_uint(f);
    u += 0x7fffu + ((u >> 16) & 1u);
    return (unsigned short)(u >> 16);
}
__device__ __forceinline__ float bf2f(unsigned short h) {
    return __uint_as_float(((unsigned)h) << 16);
}

struct IPtr4 { const int* p[4]; };
struct IPtr8 { const int* s[4]; const int* d[4]; };
struct FPtr4 { const float* p[4]; };

// ---------------- setup kernels ----------------

__global__ void hist_all(IPtr4 dst, int* __restrict__ deg) {
    int i = blockIdx.x * 256 + threadIdx.x;
    if (i >= 1500000) return;
    int e, li;
    if (i < 600000)       { e = 0; li = i; }
    else if (i < 800000)  { e = 1; li = i - 600000; }
    else if (i < 1300000) { e = 2; li = i - 800000; }
    else                  { e = 3; li = i - 1300000; }
    atomicAdd(&deg[e * S_I + dst.p[e][li]], 1);
}

__device__ __forceinline__ void blk_decode(int b, int& e, int& lb, int& N) {
    if (b < 98)       { e = 0; lb = b;       N = 100000; }
    else if (b < 196) { e = 1; lb = b - 98;  N = 100000; }
    else if (b < 216) { e = 2; lb = b - 196; N = 20000;  }
    else              { e = 3; lb = b - 216; N = 2000;   }
}

__global__ void scan_p1(const int* __restrict__ deg, int* __restrict__ bsum) {
    int tid = threadIdx.x;
    int e, lb, N;
    blk_decode(blockIdx.x, e, lb, N);
    const int* dg = deg + e * S_I;
    int base = lb * 1024 + tid * 4;
    int s = 0;
#pragma unroll
    for (int j = 0; j < 4; j++) { int i = base + j; if (i < N) s += dg[i]; }
    for (int o = 32; o > 0; o >>= 1) s += __shfl_down(s, o);
    __shared__ int wsm[4];
    if ((tid & 63) == 0) wsm[tid >> 6] = s;
    __syncthreads();
    if (tid == 0) bsum[e * 512 + lb] = wsm[0] + wsm[1] + wsm[2] + wsm[3];
}

__global__ void scan_p2(const int* __restrict__ bsum, int* __restrict__ bpre, int* __restrict__ off) {
    __shared__ int sh[256];
    int tid = threadIdx.x;
    for (int e = 0; e < 4; e++) {
        int nb = (e < 2) ? 98 : (e == 2 ? 20 : 2);
        int N  = (e < 2) ? 100000 : (e == 2 ? 20000 : 2000);
        int v = (tid < nb) ? bsum[e * 512 + tid] : 0;
        sh[tid] = v;
        __syncthreads();
        for (int s = 1; s < 256; s <<= 1) {
            int t = (tid >= s) ? sh[tid - s] : 0;
            __syncthreads();
            sh[tid] += t;
            __syncthreads();
        }
        if (tid < nb) bpre[e * 512 + tid] = sh[tid] - v;
        if (tid == 0) off[e * S_I + N] = sh[255];
        __syncthreads();
    }
}

__global__ void scan_p3(const int* __restrict__ deg, const int* __restrict__ bpre,
                        int* __restrict__ off, int* __restrict__ cur) {
    int tid = threadIdx.x;
    int e, lb, N;
    blk_decode(blockIdx.x, e, lb, N);
    const int* dg = deg + e * S_I;
    int base = lb * 1024 + tid * 4;
    int v[4], s = 0;
#pragma unroll
    for (int j = 0; j < 4; j++) { int i = base + j; v[j] = (i < N) ? dg[i] : 0; s += v[j]; }
    int lane = tid & 63, w = tid >> 6;
    int sc = s;
    for (int d = 1; d < 64; d <<= 1) { int t = __shfl_up(sc, d); if (lane >= d) sc += t; }
    __shared__ int wsm[4];
    if (lane == 63) wsm[w] = sc;
    __syncthreads();
    int wpre = 0;
    for (int ww = 0; ww < 4; ww++) if (ww < w) wpre += wsm[ww];
    int run = bpre[e * 512 + lb] + wpre + (sc - s);
#pragma unroll
    for (int j = 0; j < 4; j++) {
        int i = base + j;
        if (i < N) { off[e * S_I + i] = run; cur[e * S_I + i] = run; }
        run += v[j];
    }
}

__global__ void fillcsr_all(IPtr8 sd, int* __restrict__ cur,
                            int* __restrict__ csr_src, int* __restrict__ csr_eid) {
    int i = blockIdx.x * 256 + threadIdx.x;
    if (i >= 1500000) return;
    int e, li, eo;
    if (i < 600000)       { e = 0; li = i;           eo = 0; }
    else if (i < 800000)  { e = 1; li = i - 600000;  eo = 600000; }
    else if (i < 1300000) { e = 2; li = i - 800000;  eo = 800000; }
    else                  { e = 3; li = i - 1300000; eo = 1300000; }
    int d = sd.d[e][li];
    int p = atomicAdd(&cur[e * S_I + d], 1);
    csr_src[eo + p] = sd.s[e][li];
    csr_eid[eo + p] = li;
}

// per-(etype,dst) sum of ft rows (16-wide); one wave per dst node, 4-way + unroll-2
__global__ void ftpull_all(FPtr4 ft, const int* __restrict__ csr_eid,
                           const int* __restrict__ off, float* __restrict__ fts) {
    int gid = blockIdx.x * 256 + threadIdx.x;
    int wid = gid >> 6, lane = gid & 63;
    if (wid >= 222000) return;
    int e, n, eo;
    if (wid < 100000)      { e = 0; n = wid;          eo = 0; }
    else if (wid < 200000) { e = 1; n = wid - 100000; eo = 600000; }
    else if (wid < 220000) { e = 2; n = wid - 200000; eo = 800000; }
    else                   { e = 3; n = wid - 220000; eo = 1300000; }
    int s = off[e * S_I + n], t = off[e * S_I + n + 1];
    int sub = lane >> 4, k = lane & 15;
    const float* fp = ft.p[e];
    const int* ep = csr_eid + eo;
    float a0 = 0.f, a1 = 0.f;
    int j = s + sub;
    for (; j + 4 < t; j += 8) {
        int i0 = ep[j], i1 = ep[j + 4];
        a0 += fp[(long long)i0 * 16 + k];
        a1 += fp[(long long)i1 * 16 + k];
    }
    if (j < t) a0 += fp[(long long)ep[j] * 16 + k];
    float a = a0 + a1;
    a += __shfl_down(a, 32);
    a += __shfl_down(a, 16);
    if (lane < 16) fts[(long long)wid * 16 + k] = a;
}

// bf16 W^T tiles: slots 0-3 = W_bot(e)^T, 4 = (W_top0+W_top1)^T, 5 = W_top2^T, 6 = W_top3^T
__global__ void wprep(const float* __restrict__ convW, unsigned short* __restrict__ wt) {
    int i = blockIdx.x * 256 + threadIdx.x;
    if (i >= 229376) return;
    int l = i / 114688;
    int rem = i - l * 114688;
    int slot = rem >> 14;
    int idx = rem & 16383;
    int c = idx >> 7, k = idx & 127;
    float v;
    if (slot < 4)
        v = convW[((size_t)(l * 4 + slot) * 256 + 128 + k) * 128 + c];
    else if (slot == 4)
        v = convW[((size_t)(l * 4 + 0) * 256 + k) * 128 + c] +
            convW[((size_t)(l * 4 + 1) * 256 + k) * 128 + c];
    else
        v = convW[((size_t)(l * 4 + (slot - 3)) * 256 + k) * 128 + c];
    wt[i] = f2bf(v);
}

// W extension, transposed [slot][c][r]: rows 0-15 emlpW(e_first), 16 emlpb, 32-47 emlpW(e1,bv),
// 48 emlpb(e1), 62 conv_b sum. slot = l*3 + t.
__global__ void wext_build(const float* __restrict__ emlpW, const float* __restrict__ emlpb,
                           const float* __restrict__ convb, unsigned short* __restrict__ wext) {
    int gid = blockIdx.x * 256 + threadIdx.x;
    if (gid >= 49152) return;
    int slot = gid >> 13;
    int rem = gid & 8191;
    int c = rem >> 6, r = rem & 63;
    int l = slot / 3, t = slot - l * 3;
    int ef = (t == 0) ? 0 : (t == 1) ? 2 : 3;
    int rr = r & 31, half = r >> 5;
    int e = (t == 0) ? (half ? 1 : 0) : (half ? -1 : ef);
    float v = 0.f;
    if (e >= 0) {
        if (rr < 16)       v = emlpW[e * 2048 + rr * 128 + c];
        else if (rr == 16) v = emlpb[e * 128 + c];
    }
    if (r == 62) {
        v = convb[(l * 4 + ef) * 128 + c];
        if (t == 0) v += convb[(l * 4 + 1) * 128 + c];
    }
    wext[(long long)slot * 8192 + c * 64 + r] = f2bf(v);
}

// A extension [122000][64] bf16: gated mean-ft, gate col, const-1 col 62
__global__ void aext_build(const int* __restrict__ off, const float* __restrict__ fts,
                           unsigned short* __restrict__ aext) {
    int gid = blockIdx.x * 256 + threadIdx.x;
    if (gid >= 7808000) return;
    int wid = gid >> 6, c = gid & 63;
    int t, n;
    if (wid < 100000)      { t = 0; n = wid; }
    else if (wid < 120000) { t = 1; n = wid - 100000; }
    else                   { t = 2; n = wid - 120000; }
    int cc = c & 31, half = c >> 5;
    int e = -1;
    if (t == 0) e = half ? 1 : 0;
    else if (half == 0) e = (t == 1) ? 2 : 3;
    float v = 0.f;
    if (e >= 0) {
        int s = off[e * S_I + n], en = off[e * S_I + n + 1];
        int dg = en - s;
        if (dg > 0) {
            int fb = (e == 0) ? 0 : (e == 1) ? 100000 : (e == 2) ? 200000 : 220000;
            if (cc < 16)       v = fts[(long long)(fb + n) * 16 + cc] / (float)dg;
            else if (cc == 16) v = 1.f;
        }
    }
    if (c == 62) v = 1.f;
    aext[(long long)wid * 64 + c] = f2bf(v);
}

__global__ void h0cvt(FPtr4 h, unsigned short* __restrict__ ha) {
    long long i4 = ((long long)blockIdx.x * 256 + threadIdx.x) * 4;
    if (i4 >= 28416000ll) return;
    long long r = i4 >> 7;
    int c = (int)(i4 & 127);
    int t; long long lr;
    if (r < 100000)      { t = 0; lr = r; }
    else if (r < 120000) { t = 1; lr = r - 100000; }
    else if (r < 122000) { t = 2; lr = r - 120000; }
    else                 { t = 3; lr = r - 122000; }
    const float4 v = *(const float4*)&h.p[t][lr * 128 + c];
    ushort4 o;
    o.x = f2bf(v.x); o.y = f2bf(v.y); o.z = f2bf(v.z); o.w = f2bf(v.w);
    *(ushort4*)&ha[i4] = o;
}

// layer-1 e2 constant row: bf16(lnb3) @ bf16(Wbot_e2_l1)
__global__ void vrow_build(const float* __restrict__ lnb, const unsigned short* __restrict__ wt,
                           float* __restrict__ vrow) {
    int c = threadIdx.x;
    const unsigned short* w = wt + (size_t)(1 * 7 + 2) * 16384 + (size_t)c * 128;
    float s = 0.f;
    for (int k = 0; k < 128; k++) s += bf2f(f2bf(lnb[384 + k])) * bf2f(w[k]);
    vrow[c] = s;
}

// ---------------- pure gather: ho[n,:] = sum_e mean_z(e,n) ----------------
__device__ __forceinline__ void acc8(float* t, uint4 v) {
    t[0] += __uint_as_float(v.x << 16);
    t[1] += __uint_as_float(v.x & 0xffff0000u);
    t[2] += __uint_as_float(v.y << 16);
    t[3] += __uint_as_float(v.y & 0xffff0000u);
    t[4] += __uint_as_float(v.z << 16);
    t[5] += __uint_as_float(v.z & 0xffff0000u);
    t[6] += __uint_as_float(v.w << 16);
    t[7] += __uint_as_float(v.w & 0xffff0000u);
}

__global__ __launch_bounds__(256) void pull_all(int l, const int* __restrict__ off,
        const int* __restrict__ csr_src, const unsigned short* __restrict__ za,
        const float* __restrict__ vrow, unsigned short* __restrict__ hout) {
    long long gid = (long long)blockIdx.x * 256 + threadIdx.x;
    int wid = (int)(gid >> 6), lane = (int)(gid & 63);
    if (wid >= 122000) return;
    int t, n;
    if (wid < 100000)      { t = 0; n = wid; }
    else if (wid < 120000) { t = 1; n = wid - 100000; }
    else                   { t = 2; n = wid - 120000; }
    int sub = lane >> 4, k8 = (lane & 15) * 8;
    float a[8];
#pragma unroll
    for (int i = 0; i < 8; i++) a[i] = 0.f;
    int ef = (t == 0) ? 0 : (t == 1) ? 2 : 3;
    int ne = (t == 0) ? 2 : 1;
    for (int ii = 0; ii < ne; ii++) {
        int e = ef + ii;
        int s = off[e * S_I + n], en = off[e * S_I + n + 1];
        int cnt = en - s;
        if (cnt <= 0) continue;
        if (e == 2 && l == 1) {
            if (sub == 0) {
                float4 v0 = *(const float4*)&vrow[k8];
                float4 v1 = *(const float4*)&vrow[k8 + 4];
                a[0] += v0.x; a[1] += v0.y; a[2] += v0.z; a[3] += v0.w;
                a[4] += v1.x; a[5] += v1.y; a[6] += v1.z; a[7] += v1.w;
            }
            continue;
        }
        int eo   = (e == 0) ? 0 : (e == 1) ? 600000 : (e == 2) ? 800000 : 1300000;
        long long zo = (e == 0) ? 0 : (e == 1) ? 20000 : (e == 2) ? 22000 : 122000;
        const int* cs = csr_src + eo + s;
        const unsigned short* zb = za + zo * 128;
        float t0[8], t1[8];
#pragma unroll
        for (int i = 0; i < 8; i++) { t0[i] = 0.f; t1[i] = 0.f; }
        int j = sub;
        for (; j + 4 < cnt; j += 8) {
            int i0 = cs[j], i1 = cs[j + 4];
            uint4 v0 = *(const uint4*)&zb[(long long)i0 * 128 + k8];
            uint4 v1 = *(const uint4*)&zb[(long long)i1 * 128 + k8];
            acc8(t0, v0);
            acc8(t1, v1);
        }
        if (j < cnt) {
            int i0 = cs[j];
            uint4 v0 = *(const uint4*)&zb[(long long)i0 * 128 + k8];
            acc8(t0, v0);
        }
        float inv = 1.f / (float)cnt;
#pragma unroll
        for (int i = 0; i < 8; i++) a[i] += (t0[i] + t1[i]) * inv;
    }
#pragma unroll
    for (int i = 0; i < 8; i++) {
        a[i] += __shfl_xor(a[i], 16);
        a[i] += __shfl_xor(a[i], 32);
    }
    if (sub == 0) {
        uint4 p;
        p.x = (unsigned)f2bf(a[0]) | ((unsigned)f2bf(a[1]) << 16);
        p.y = (unsigned)f2bf(a[2]) | ((unsigned)f2bf(a[3]) << 16);
        p.z = (unsigned)f2bf(a[4]) | ((unsigned)f2bf(a[5]) << 16);
        p.w = (unsigned)f2bf(a[6]) | ((unsigned)f2bf(a[7]) << 16);
        *(uint4*)&hout[(long long)wid * 128 + k8] = p;
    }
}

// ---------------- merged z-GEMM: za = ha @ W_bot (bf16 out), all edge types ----------------
__global__ __launch_bounds__(256, 2) void zgemm(int l, const unsigned short* __restrict__ ha,
        const unsigned short* __restrict__ wt, unsigned short* __restrict__ za) {
    __shared__ unsigned short As[16384];
    __shared__ unsigned short Bs[16384];
    int b = blockIdx.x;
    int e, lb, M; long long aoff, zoff;
    if (l == 0) {
        if (b < 157)      { e = 0; lb = b;       M = 20000;  aoff = 100000; zoff = 0; }
        else if (b < 173) { e = 1; lb = b - 157; M = 2000;   aoff = 120000; zoff = 20000; }
        else if (b < 955) { e = 2; lb = b - 173; M = 100000; aoff = 122000; zoff = 22000; }
        else              { e = 3; lb = b - 955; M = 100000; aoff = 0;      zoff = 122000; }
    } else {
        if (b < 157)      { e = 0; lb = b;       M = 20000;  aoff = 100000; zoff = 0; }
        else if (b < 173) { e = 1; lb = b - 157; M = 2000;   aoff = 120000; zoff = 20000; }
        else              { e = 3; lb = b - 173; M = 100000; aoff = 0;      zoff = 122000; }
    }
    const unsigned short* A  = ha + aoff * 128;
    const unsigned short* Wt = wt + (size_t)(l * 7 + e) * 16384;
    unsigned short* outb = za + zoff * 128;
    int tid = threadIdx.x;
    long long row0 = (long long)lb * 128;
#pragma unroll
    for (int i = 0; i < 8; i++) {
        int idx = tid + i * 256;
        int m = idx >> 4, c = idx & 15;
        int sw = c ^ (m & 15);
        uint4 va = make_uint4(0u, 0u, 0u, 0u);
        long long gr = row0 + m;
        if (gr < M) va = *(const uint4*)&A[gr * 128 + c * 8];
        *(uint4*)&As[m * 128 + sw * 8] = va;
        uint4 wv = *(const uint4*)&Wt[m * 128 + c * 8];
        *(uint4*)&Bs[m * 128 + sw * 8] = wv;
    }
    __syncthreads();
    int lane = tid & 63, w = tid >> 6;
    int q = lane >> 4, ml = lane & 15;
    v4f acc[2][8];
#pragma unroll
    for (int i = 0; i < 2; i++)
#pragma unroll
        for (int j = 0; j < 8; j++) acc[i][j] = (v4f){0.f, 0.f, 0.f, 0.f};
#pragma unroll
    for (int kc = 0; kc < 4; kc++) {
        int ch = (4 * kc + q) ^ ml;
        v8s af[2], bf[8];
#pragma unroll
        for (int i = 0; i < 2; i++) af[i] = *(const v8s*)&As[(32 * w + 16 * i + ml) * 128 + ch * 8];
#pragma unroll
        for (int j = 0; j < 8; j++) bf[j] = *(const v8s*)&Bs[(16 * j + ml) * 128 + ch * 8];
#pragma unroll
        for (int i = 0; i < 2; i++)
#pragma unroll
            for (int j = 0; j < 8; j++)
                acc[i][j] = __builtin_amdgcn_mfma_f32_16x16x32_bf16(af[i], bf[j], acc[i][j], 0, 0, 0);
    }
#pragma unroll
    for (int i = 0; i < 2; i++)
#pragma unroll
        for (int r = 0; r < 4; r++) {
            long long row = row0 + 32 * w + 16 * i + q * 4 + r;
            if (row < M) {
#pragma unroll
                for (int j = 0; j < 8; j++)
                    outb[row * 128 + 16 * j + ml] = f2bf(acc[i][j][r]);
            }
        }
}

// ---------------- merged self-GEMM (K=192 via ext phase) + Cadd + LayerNorm ----------------
__global__ __launch_bounds__(256, 2) void selfgemm(int l, unsigned short* __restrict__ ha,
        const unsigned short* __restrict__ wt, const unsigned short* __restrict__ wext,
        const unsigned short* __restrict__ aext, const unsigned short* __restrict__ ho,
        float* __restrict__ outf, const float* __restrict__ lng, const float* __restrict__ lnb) {
    __shared__ unsigned short As[16384];
    __shared__ unsigned short Bs[16384];
    int b = blockIdx.x;
    int t, lb, M; long long hoff;
    if (b < 782)      { t = 0; lb = b;       M = 100000; hoff = 0; }
    else if (b < 939) { t = 1; lb = b - 782; M = 20000;  hoff = 100000; }
    else              { t = 2; lb = b - 939; M = 2000;   hoff = 120000; }
    const unsigned short* A    = ha + hoff * 128;
    const unsigned short* Ax   = aext + hoff * 64;
    const unsigned short* Wt_  = wt + (size_t)(l * 7 + 4 + t) * 16384;
    const unsigned short* Wx   = wext + (size_t)(l * 3 + t) * 8192;
    const unsigned short* Cadd = ho + hoff * 128;
    const float* g  = lng + t * 128;
    const float* bb = lnb + t * 128;
    int tid = threadIdx.x;
    long long row0 = (long long)lb * 128;
    // phase A: K 0..127
#pragma unroll
    for (int i = 0; i < 8; i++) {
        int idx = tid + i * 256;
        int m = idx >> 4, c = idx & 15;
        int sw = c ^ (m & 15);
        uint4 va = make_uint4(0u, 0u, 0u, 0u);
        long long gr = row0 + m;
        if (gr < M) va = *(const uint4*)&A[gr * 128 + c * 8];
        *(uint4*)&As[m * 128 + sw * 8] = va;
        uint4 wv = *(const uint4*)&Wt_[m * 128 + c * 8];
        *(uint4*)&Bs[m * 128 + sw * 8] = wv;
    }
    __syncthreads();
    int lane = tid & 63, w = tid >> 6;
    int q = lane >> 4, ml = lane & 15;
    v4f acc[2][8];
#pragma unroll
    for (int i = 0; i < 2; i++)
#pragma unroll
        for (int j = 0; j < 8; j++) acc[i][j] = (v4f){0.f, 0.f, 0.f, 0.f};
#pragma unroll
    for (int kc = 0; kc < 4; kc++) {
        int ch = (4 * kc + q) ^ ml;
        v8s af[2], bf[8];
#pragma unroll
        for (int i = 0; i < 2; i++) af[i] = *(const v8s*)&As[(32 * w + 16 * i + ml) * 128 + ch * 8];
#pragma unroll
        for (int j = 0; j < 8; j++) bf[j] = *(const v8s*)&Bs[(16 * j + ml) * 128 + ch * 8];
#pragma unroll
        for (int i = 0; i < 2; i++)
#pragma unroll
            for (int j = 0; j < 8; j++)
                acc[i][j] = __builtin_amdgcn_mfma_f32_16x16x32_bf16(af[i], bf[j], acc[i][j], 0, 0, 0);
    }
    __syncthreads();
    // phase B: K 128..191 (ext)
#pragma unroll
    for (int i = 0; i < 4; i++) {
        int idx = tid + i * 256;
        int m = idx >> 3, c = idx & 7;
        int sw = c ^ (m & 7);
        uint4 va = make_uint4(0u, 0u, 0u, 0u);
        long long gr = row0 + m;
        if (gr < M) va = *(const uint4*)&Ax[gr * 64 + c * 8];
        *(uint4*)&As[m * 64 + sw * 8] = va;
        uint4 wv = *(const uint4*)&Wx[m * 64 + c * 8];
        *(uint4*)&Bs[m * 64 + sw * 8] = wv;
    }
    __syncthreads();
#pragma unroll
    for (int kc = 0; kc < 2; kc++) {
        int ch = (4 * kc + q) ^ (ml & 7);
        v8s af[2], bf[8];
#pragma unroll
        for (int i = 0; i < 2; i++) af[i] = *(const v8s*)&As[(32 * w + 16 * i + ml) * 64 + ch * 8];
#pragma unroll
        for (int j = 0; j < 8; j++) bf[j] = *(const v8s*)&Bs[(16 * j + ml) * 64 + ch * 8];
#pragma unroll
        for (int i = 0; i < 2; i++)
#pragma unroll
            for (int j = 0; j < 8; j++)
                acc[i][j] = __builtin_amdgcn_mfma_f32_16x16x32_bf16(af[i], bf[j], acc[i][j], 0, 0, 0);
    }
    // epilogue: + Cadd (bf16), LayerNorm, store
    float gv[8], bv[8];
#pragma unroll
    for (int j = 0; j < 8; j++) { gv[j] = g[16 * j + ml]; bv[j] = bb[16 * j + ml]; }
    unsigned short* outb = ha + hoff * 128;
    float* outF = outf + hoff * 128;
#pragma unroll
    for (int i = 0; i < 2; i++) {
#pragma unroll
        for (int r = 0; r < 4; r++) {
            long long row = row0 + 32 * w + 16 * i + q * 4 + r;
            bool valid = row < M;
            float s = 0.f, s2 = 0.f;
#pragma unroll
            for (int j = 0; j < 8; j++) {
                float v = acc[i][j][r];
                if (valid) v += bf2f(Cadd[row * 128 + 16 * j + ml]);
                acc[i][j][r] = v;
                s += v; s2 += v * v;
            }
#pragma unroll
            for (int msk = 1; msk < 16; msk <<= 1) {
                s  += __shfl_xor(s,  msk);
                s2 += __shfl_xor(s2, msk);
            }
            float mean = s * 0.0078125f;
            float var  = s2 * 0.0078125f - mean * mean;
            float rs = rsqrtf(var + 1e-5f);
            if (valid) {
#pragma unroll
                for (int j = 0; j < 8; j++) {
                    float v = (acc[i][j][r] - mean) * rs * gv[j] + bv[j];
                    if (l == 0) outb[row * 128 + 16 * j + ml] = f2bf(v);
                    else        outF[row * 128 + 16 * j + ml] = v;
                }
            }
        }
    }
}

__global__ void fill_dn(float* __restrict__ of, const float* __restrict__ lnb3) {
    long long i4 = ((long long)blockIdx.x * 256 + threadIdx.x) * 4;
    if (i4 >= 12800000ll) return;
    int c = (int)(i4 & 127);
    *(float4*)&of[i4] = make_float4(lnb3[c], lnb3[c + 1], lnb3[c + 2], lnb3[c + 3]);
}

// ---------------- host launch ----------------
extern "C" void kernel_launch(void* const* d_in, const int* in_sizes, int n_in,
                              void* d_out, int out_size, void* d_ws, size_t ws_size,
                              hipStream_t stream) {
    if (ws_size < WS_NEEDED) return;

    const float* h0[4] = {(const float*)d_in[0], (const float*)d_in[1],
                          (const float*)d_in[2], (const float*)d_in[3]};
    const float* ftp[4] = {(const float*)d_in[4], (const float*)d_in[5],
                           (const float*)d_in[6], (const float*)d_in[7]};
    const float* convW = (const float*)d_in[8];
    const float* convb = (const float*)d_in[9];
    const float* emlpW = (const float*)d_in[10];
    const float* emlpb = (const float*)d_in[11];
    const float* lng   = (const float*)d_in[12];
    const float* lnb   = (const float*)d_in[13];
    const int* srcp[4] = {(const int*)d_in[14], (const int*)d_in[16],
                          (const int*)d_in[18], (const int*)d_in[20]};
    const int* dstp[4] = {(const int*)d_in[15], (const int*)d_in[17],
                          (const int*)d_in[19], (const int*)d_in[21]};
    char* ws = (char*)d_ws;
    float* out = (float*)d_out;

    int* deg = (int*)(ws + DEG_B);
    int* off = (int*)(ws + OFF_B);
    int* cur = (int*)(ws + CUR_B);
    int* csr_src = (int*)(ws + CSRS_B);
    int* csr_eid = (int*)(ws + CSRE_B);
    float* fts = (float*)(ws + FTS_B);
    int* bsum = (int*)(ws + BSUM_B);
    int* bpre = (int*)(ws + BPRE_B);
    unsigned short* wt   = (unsigned short*)(ws + WT_B);
    unsigned short* wext = (unsigned short*)(ws + WEXT_B);
    float* vrow = (float*)(ws + VROW_B);
    unsigned short* aext = (unsigned short*)(ws + AEXT_B);
    unsigned short* ha = (unsigned short*)(ws + HA_B);
    unsigned short* za = (unsigned short*)(ws + ZA_B);
    unsigned short* ho = (unsigned short*)(ws + HO_B);

    hipMemsetAsync(deg, 0, 4 * S_I * sizeof(int), stream);
    IPtr4 dsts; for (int e = 0; e < 4; e++) dsts.p[e] = dstp[e];
    hist_all<<<5860, 256, 0, stream>>>(dsts, deg);
    scan_p1<<<218, 256, 0, stream>>>(deg, bsum);
    scan_p2<<<1, 256, 0, stream>>>(bsum, bpre, off);
    scan_p3<<<218, 256, 0, stream>>>(deg, bpre, off, cur);
    IPtr8 sd;
    for (int e = 0; e < 4; e++) { sd.s[e] = srcp[e]; sd.d[e] = dstp[e]; }
    fillcsr_all<<<5860, 256, 0, stream>>>(sd, cur, csr_src, csr_eid);
    FPtr4 ftq; for (int e = 0; e < 4; e++) ftq.p[e] = ftp[e];
    ftpull_all<<<55500, 256, 0, stream>>>(ftq, csr_eid, off, fts);
    wprep<<<896, 256, 0, stream>>>(convW, wt);
    wext_build<<<192, 256, 0, stream>>>(emlpW, emlpb, convb, wext);
    vrow_build<<<1, 128, 0, stream>>>(lnb, wt, vrow);
    FPtr4 hq; for (int t = 0; t < 4; t++) hq.p[t] = h0[t];
    h0cvt<<<27750, 256, 0, stream>>>(hq, ha);
    aext_build<<<30500, 256, 0, stream>>>(off, fts, aext);

    for (int l = 0; l < 2; l++) {
        zgemm<<<(l == 0) ? 1737 : 955, 256, 0, stream>>>(l, ha, wt, za);
        pull_all<<<30500, 256, 0, stream>>>(l, off, csr_src, za, vrow, ho);
        selfgemm<<<955, 256, 0, stream>>>(l, ha, wt, wext, aext, ho, out, lng, lnb);
    }
    fill_dn<<<12500, 256, 0, stream>>>(out + 122000ll * 128, lnb + 384);
}

// Round 4
// 885.643 us; speedup vs baseline: 2.5233x; 1.0215x over previous
//
#include <hip/hip_runtime.h>

typedef short v8s __attribute__((ext_vector_type(8)));
typedef float v4f __attribute__((ext_vector_type(4)));

#define S_I 100352

// ---------------- workspace byte offsets (256-aligned) ----------------
#define DEG_B   0ull
#define OFF_B   1605632ull
#define CUR_B   3211264ull
#define CSRS_B  4816896ull
#define FTS_B   16817152ull
#define BSUM_B  31025152ull
#define BPRE_B  31033344ull
#define WT_B    31041536ull
#define WEXT_B  31500288ull
#define VROW_B  31598592ull
#define AEXT_B  31599104ull
#define HA_B    47215104ull
#define ZA_B    104047104ull
#define HO_B    160879104ull
#define WS_NEEDED 192111104ull

__device__ __forceinline__ unsigned short f2bf(float f) {
    unsigned u = __float_as_uint(f);
    u += 0x7fffu + ((u >> 16) & 1u);
    return (unsigned short)(u >> 16);
}
__device__ __forceinline__ float bf2f(unsigned short h) {
    return __uint_as_float(((unsigned)h) << 16);
}

struct IPtr4 { const int* p[4]; };
struct IPtr8 { const int* s[4]; const int* d[4]; };
struct FPtr4 { const float* p[4]; };

// ---------------- fused histogram + ft scatter-add (16 threads per edge) ----------------
__global__ void hist_ft(IPtr4 dst, FPtr4 ft, int* __restrict__ deg, float* __restrict__ fts) {
    long long gid = (long long)blockIdx.x * 256 + threadIdx.x;
    if (gid >= 24000000ll) return;
    int k = (int)(gid & 15);
    int i = (int)(gid >> 4);
    int e, li, fb;
    if (i < 600000)       { e = 0; li = i;           fb = 0; }
    else if (i < 800000)  { e = 1; li = i - 600000;  fb = 100000; }
    else if (i < 1300000) { e = 2; li = i - 800000;  fb = 200000; }
    else                  { e = 3; li = i - 1300000; fb = 220000; }
    int d = dst.p[e][li];
    float v = ft.p[e][(long long)li * 16 + k];
    atomicAdd(&fts[(long long)(fb + d) * 16 + k], v);
    if (k == 0) atomicAdd(&deg[e * S_I + d], 1);
}

__device__ __forceinline__ void blk_decode(int b, int& e, int& lb, int& N) {
    if (b < 98)       { e = 0; lb = b;       N = 100000; }
    else if (b < 196) { e = 1; lb = b - 98;  N = 100000; }
    else if (b < 216) { e = 2; lb = b - 196; N = 20000;  }
    else              { e = 3; lb = b - 216; N = 2000;   }
}

__global__ void scan_p1(const int* __restrict__ deg, int* __restrict__ bsum) {
    int tid = threadIdx.x;
    int e, lb, N;
    blk_decode(blockIdx.x, e, lb, N);
    const int* dg = deg + e * S_I;
    int base = lb * 1024 + tid * 4;
    int s = 0;
#pragma unroll
    for (int j = 0; j < 4; j++) { int i = base + j; if (i < N) s += dg[i]; }
    for (int o = 32; o > 0; o >>= 1) s += __shfl_down(s, o);
    __shared__ int wsm[4];
    if ((tid & 63) == 0) wsm[tid >> 6] = s;
    __syncthreads();
    if (tid == 0) bsum[e * 512 + lb] = wsm[0] + wsm[1] + wsm[2] + wsm[3];
}

__global__ void scan_p2(const int* __restrict__ bsum, int* __restrict__ bpre, int* __restrict__ off) {
    __shared__ int sh[256];
    int tid = threadIdx.x;
    for (int e = 0; e < 4; e++) {
        int nb = (e < 2) ? 98 : (e == 2 ? 20 : 2);
        int N  = (e < 2) ? 100000 : (e == 2 ? 20000 : 2000);
        int v = (tid < nb) ? bsum[e * 512 + tid] : 0;
        sh[tid] = v;
        __syncthreads();
        for (int s = 1; s < 256; s <<= 1) {
            int t = (tid >= s) ? sh[tid - s] : 0;
            __syncthreads();
            sh[tid] += t;
            __syncthreads();
        }
        if (tid < nb) bpre[e * 512 + tid] = sh[tid] - v;
        if (tid == 0) off[e * S_I + N] = sh[255];
        __syncthreads();
    }
}

__global__ void scan_p3(const int* __restrict__ deg, const int* __restrict__ bpre,
                        int* __restrict__ off, int* __restrict__ cur) {
    int tid = threadIdx.x;
    int e, lb, N;
    blk_decode(blockIdx.x, e, lb, N);
    const int* dg = deg + e * S_I;
    int base = lb * 1024 + tid * 4;
    int v[4], s = 0;
#pragma unroll
    for (int j = 0; j < 4; j++) { int i = base + j; v[j] = (i < N) ? dg[i] : 0; s += v[j]; }
    int lane = tid & 63, w = tid >> 6;
    int sc = s;
    for (int d = 1; d < 64; d <<= 1) { int t = __shfl_up(sc, d); if (lane >= d) sc += t; }
    __shared__ int wsm[4];
    if (lane == 63) wsm[w] = sc;
    __syncthreads();
    int wpre = 0;
    for (int ww = 0; ww < 4; ww++) if (ww < w) wpre += wsm[ww];
    int run = bpre[e * 512 + lb] + wpre + (sc - s);
#pragma unroll
    for (int j = 0; j < 4; j++) {
        int i = base + j;
        if (i < N) { off[e * S_I + i] = run; cur[e * S_I + i] = run; }
        run += v[j];
    }
}

__global__ void fillcsr_all(IPtr8 sd, int* __restrict__ cur, int* __restrict__ csr_src) {
    int i = blockIdx.x * 256 + threadIdx.x;
    if (i >= 1500000) return;
    int e, li, eo;
    if (i < 600000)       { e = 0; li = i;           eo = 0; }
    else if (i < 800000)  { e = 1; li = i - 600000;  eo = 600000; }
    else if (i < 1300000) { e = 2; li = i - 800000;  eo = 800000; }
    else                  { e = 3; li = i - 1300000; eo = 1300000; }
    int d = sd.d[e][li];
    int p = atomicAdd(&cur[e * S_I + d], 1);
    csr_src[eo + p] = sd.s[e][li];
}

// merged constant prep: wt tiles + wext + vrow (vrow computed from convW directly)
__global__ void const_build(const float* __restrict__ convW, const float* __restrict__ emlpW,
                            const float* __restrict__ emlpb, const float* __restrict__ convb,
                            const float* __restrict__ lnb, unsigned short* __restrict__ wt,
                            unsigned short* __restrict__ wext, float* __restrict__ vrow) {
    int gid = blockIdx.x * 256 + threadIdx.x;
    if (gid < 229376) {
        int i = gid;
        int l = i / 114688;
        int rem = i - l * 114688;
        int slot = rem >> 14;
        int idx = rem & 16383;
        int c = idx >> 7, k = idx & 127;
        float v;
        if (slot < 4)
            v = convW[((size_t)(l * 4 + slot) * 256 + 128 + k) * 128 + c];
        else if (slot == 4)
            v = convW[((size_t)(l * 4 + 0) * 256 + k) * 128 + c] +
                convW[((size_t)(l * 4 + 1) * 256 + k) * 128 + c];
        else
            v = convW[((size_t)(l * 4 + (slot - 3)) * 256 + k) * 128 + c];
        wt[i] = f2bf(v);
    } else if (gid < 229376 + 49152) {
        int g = gid - 229376;
        int slot = g >> 13;
        int rem = g & 8191;
        int c = rem >> 6, r = rem & 63;
        int l = slot / 3, t = slot - l * 3;
        int ef = (t == 0) ? 0 : (t == 1) ? 2 : 3;
        int rr = r & 31, half = r >> 5;
        int e = (t == 0) ? (half ? 1 : 0) : (half ? -1 : ef);
        float v = 0.f;
        if (e >= 0) {
            if (rr < 16)       v = emlpW[e * 2048 + rr * 128 + c];
            else if (rr == 16) v = emlpb[e * 128 + c];
        }
        if (r == 62) {
            v = convb[(l * 4 + ef) * 128 + c];
            if (t == 0) v += convb[(l * 4 + 1) * 128 + c];
        }
        wext[(long long)slot * 8192 + c * 64 + r] = f2bf(v);
    } else if (gid < 229376 + 49152 + 128) {
        int c = gid - 229376 - 49152;
        // vrow[c] = bf16(lnb3) . bf16(Wbot_e2_l1[:,c])
        float s = 0.f;
        for (int k = 0; k < 128; k++)
            s += bf2f(f2bf(lnb[384 + k])) * bf2f(f2bf(convW[((size_t)(1 * 4 + 2) * 256 + 128 + k) * 128 + c]));
        vrow[c] = s;
    }
}

// A extension [122000][64] bf16: gated mean-ft, gate col, const-1 col 62
__global__ void aext_build(const int* __restrict__ off, const float* __restrict__ fts,
                           unsigned short* __restrict__ aext) {
    int gid = blockIdx.x * 256 + threadIdx.x;
    if (gid >= 7808000) return;
    int wid = gid >> 6, c = gid & 63;
    int t, n;
    if (wid < 100000)      { t = 0; n = wid; }
    else if (wid < 120000) { t = 1; n = wid - 100000; }
    else                   { t = 2; n = wid - 120000; }
    int cc = c & 31, half = c >> 5;
    int e = -1;
    if (t == 0) e = half ? 1 : 0;
    else if (half == 0) e = (t == 1) ? 2 : 3;
    float v = 0.f;
    if (e >= 0) {
        int s = off[e * S_I + n], en = off[e * S_I + n + 1];
        int dg = en - s;
        if (dg > 0) {
            int fb = (e == 0) ? 0 : (e == 1) ? 100000 : (e == 2) ? 200000 : 220000;
            if (cc < 16)       v = fts[(long long)(fb + n) * 16 + cc] / (float)dg;
            else if (cc == 16) v = 1.f;
        }
    }
    if (c == 62) v = 1.f;
    aext[(long long)wid * 64 + c] = f2bf(v);
}

__global__ void h0cvt(FPtr4 h, unsigned short* __restrict__ ha) {
    long long i4 = ((long long)blockIdx.x * 256 + threadIdx.x) * 4;
    if (i4 >= 28416000ll) return;
    long long r = i4 >> 7;
    int c = (int)(i4 & 127);
    int t; long long lr;
    if (r < 100000)      { t = 0; lr = r; }
    else if (r < 120000) { t = 1; lr = r - 100000; }
    else if (r < 122000) { t = 2; lr = r - 120000; }
    else                 { t = 3; lr = r - 122000; }
    const float4 v = *(const float4*)&h.p[t][lr * 128 + c];
    ushort4 o;
    o.x = f2bf(v.x); o.y = f2bf(v.y); o.z = f2bf(v.z); o.w = f2bf(v.w);
    *(ushort4*)&ha[i4] = o;
}

// ---------------- pure gather: ho[n,:] = sum_e mean_z(e,n) ----------------
__device__ __forceinline__ void acc8(float* t, uint4 v) {
    t[0] += __uint_as_float(v.x << 16);
    t[1] += __uint_as_float(v.x & 0xffff0000u);
    t[2] += __uint_as_float(v.y << 16);
    t[3] += __uint_as_float(v.y & 0xffff0000u);
    t[4] += __uint_as_float(v.z << 16);
    t[5] += __uint_as_float(v.z & 0xffff0000u);
    t[6] += __uint_as_float(v.w << 16);
    t[7] += __uint_as_float(v.w & 0xffff0000u);
}

__global__ __launch_bounds__(256) void pull_all(int l, const int* __restrict__ off,
        const int* __restrict__ csr_src, const unsigned short* __restrict__ za,
        const float* __restrict__ vrow, unsigned short* __restrict__ hout) {
    long long gid = (long long)blockIdx.x * 256 + threadIdx.x;
    int wid = (int)(gid >> 6), lane = (int)(gid & 63);
    if (wid >= 122000) return;
    int t, n;
    if (wid < 100000)      { t = 0; n = wid; }
    else if (wid < 120000) { t = 1; n = wid - 100000; }
    else                   { t = 2; n = wid - 120000; }
    int sub = lane >> 4, k8 = (lane & 15) * 8;
    float a[8];
#pragma unroll
    for (int i = 0; i < 8; i++) a[i] = 0.f;
    int ef = (t == 0) ? 0 : (t == 1) ? 2 : 3;
    int ne = (t == 0) ? 2 : 1;
    for (int ii = 0; ii < ne; ii++) {
        int e = ef + ii;
        int s = off[e * S_I + n], en = off[e * S_I + n + 1];
        int cnt = en - s;
        if (cnt <= 0) continue;
        if (e == 2 && l == 1) {
            if (sub == 0) {
                float4 v0 = *(const float4*)&vrow[k8];
                float4 v1 = *(const float4*)&vrow[k8 + 4];
                a[0] += v0.x; a[1] += v0.y; a[2] += v0.z; a[3] += v0.w;
                a[4] += v1.x; a[5] += v1.y; a[6] += v1.z; a[7] += v1.w;
            }
            continue;
        }
        int eo   = (e == 0) ? 0 : (e == 1) ? 600000 : (e == 2) ? 800000 : 1300000;
        long long zo = (e == 0) ? 0 : (e == 1) ? 20000 : (e == 2) ? 22000 : 122000;
        const int* cs = csr_src + eo + s;
        const unsigned short* zb = za + zo * 128;
        float t0[8], t1[8];
#pragma unroll
        for (int i = 0; i < 8; i++) { t0[i] = 0.f; t1[i] = 0.f; }
        int j = sub;
        for (; j + 4 < cnt; j += 8) {
            int i0 = cs[j], i1 = cs[j + 4];
            uint4 v0 = *(const uint4*)&zb[(long long)i0 * 128 + k8];
            uint4 v1 = *(const uint4*)&zb[(long long)i1 * 128 + k8];
            acc8(t0, v0);
            acc8(t1, v1);
        }
        if (j < cnt) {
            int i0 = cs[j];
            uint4 v0 = *(const uint4*)&zb[(long long)i0 * 128 + k8];
            acc8(t0, v0);
        }
        float inv = 1.f / (float)cnt;
#pragma unroll
        for (int i = 0; i < 8; i++) a[i] += (t0[i] + t1[i]) * inv;
    }
#pragma unroll
    for (int i = 0; i < 8; i++) {
        a[i] += __shfl_xor(a[i], 16);
        a[i] += __shfl_xor(a[i], 32);
    }
    if (sub == 0) {
        uint4 p;
        p.x = (unsigned)f2bf(a[0]) | ((unsigned)f2bf(a[1]) << 16);
        p.y = (unsigned)f2bf(a[2]) | ((unsigned)f2bf(a[3]) << 16);
        p.z = (unsigned)f2bf(a[4]) | ((unsigned)f2bf(a[5]) << 16);
        p.w = (unsigned)f2bf(a[6]) | ((unsigned)f2bf(a[7]) << 16);
        *(uint4*)&hout[(long long)wid * 128 + k8] = p;
    }
}

// ---------------- merged z-GEMM: za = ha @ W_bot (bf16 out), all edge types ----------------
__global__ __launch_bounds__(256, 2) void zgemm(int l, const unsigned short* __restrict__ ha,
        const unsigned short* __restrict__ wt, unsigned short* __restrict__ za) {
    __shared__ unsigned short As[16384];
    __shared__ unsigned short Bs[16384];
    int b = blockIdx.x;
    int e, lb, M; long long aoff, zoff;
    if (l == 0) {
        if (b < 157)      { e = 0; lb = b;       M = 20000;  aoff = 100000; zoff = 0; }
        else if (b < 173) { e = 1; lb = b - 157; M = 2000;   aoff = 120000; zoff = 20000; }
        else if (b < 955) { e = 2; lb = b - 173; M = 100000; aoff = 122000; zoff = 22000; }
        else              { e = 3; lb = b - 955; M = 100000; aoff = 0;      zoff = 122000; }
    } else {
        if (b < 157)      { e = 0; lb = b;       M = 20000;  aoff = 100000; zoff = 0; }
        else if (b < 173) { e = 1; lb = b - 157; M = 2000;   aoff = 120000; zoff = 20000; }
        else              { e = 3; lb = b - 173; M = 100000; aoff = 0;      zoff = 122000; }
    }
    const unsigned short* A  = ha + aoff * 128;
    const unsigned short* Wt = wt + (size_t)(l * 7 + e) * 16384;
    unsigned short* outb = za + zoff * 128;
    int tid = threadIdx.x;
    long long row0 = (long long)lb * 128;
#pragma unroll
    for (int i = 0; i < 8; i++) {
        int idx = tid + i * 256;
        int m = idx >> 4, c = idx & 15;
        int sw = c ^ (m & 15);
        uint4 va = make_uint4(0u, 0u, 0u, 0u);
        long long gr = row0 + m;
        if (gr < M) va = *(const uint4*)&A[gr * 128 + c * 8];
        *(uint4*)&As[m * 128 + sw * 8] = va;
        uint4 wv = *(const uint4*)&Wt[m * 128 + c * 8];
        *(uint4*)&Bs[m * 128 + sw * 8] = wv;
    }
    __syncthreads();
    int lane = tid & 63, w = tid >> 6;
    int q = lane >> 4, ml = lane & 15;
    v4f acc[2][8];
#pragma unroll
    for (int i = 0; i < 2; i++)
#pragma unroll
        for (int j = 0; j < 8; j++) acc[i][j] = (v4f){0.f, 0.f, 0.f, 0.f};
#pragma unroll
    for (int kc = 0; kc < 4; kc++) {
        int ch = (4 * kc + q) ^ ml;
        v8s af[2], bf[8];
#pragma unroll
        for (int i = 0; i < 2; i++) af[i] = *(const v8s*)&As[(32 * w + 16 * i + ml) * 128 + ch * 8];
#pragma unroll
        for (int j = 0; j < 8; j++) bf[j] = *(const v8s*)&Bs[(16 * j + ml) * 128 + ch * 8];
#pragma unroll
        for (int i = 0; i < 2; i++)
#pragma unroll
            for (int j = 0; j < 8; j++)
                acc[i][j] = __builtin_amdgcn_mfma_f32_16x16x32_bf16(af[i], bf[j], acc[i][j], 0, 0, 0);
    }
#pragma unroll
    for (int i = 0; i < 2; i++)
#pragma unroll
        for (int r = 0; r < 4; r++) {
            long long row = row0 + 32 * w + 16 * i + q * 4 + r;
            if (row < M) {
#pragma unroll
                for (int j = 0; j < 8; j++)
                    outb[row * 128 + 16 * j + ml] = f2bf(acc[i][j][r]);
            }
        }
}

// ---------------- merged self-GEMM (K=192 via ext phase) + Cadd + LayerNorm ----------------
__global__ __launch_bounds__(256, 2) void selfgemm(int l, unsigned short* __restrict__ ha,
        const unsigned short* __restrict__ wt, const unsigned short* __restrict__ wext,
        const unsigned short* __restrict__ aext, const unsigned short* __restrict__ ho,
        float* __restrict__ outf, const float* __restrict__ lng, const float* __restrict__ lnb) {
    __shared__ unsigned short As[16384];
    __shared__ unsigned short Bs[16384];
    int b = blockIdx.x;
    int t, lb, M; long long hoff;
    if (b < 782)      { t = 0; lb = b;       M = 100000; hoff = 0; }
    else if (b < 939) { t = 1; lb = b - 782; M = 20000;  hoff = 100000; }
    else              { t = 2; lb = b - 939; M = 2000;   hoff = 120000; }
    const unsigned short* A    = ha + hoff * 128;
    const unsigned short* Ax   = aext + hoff * 64;
    const unsigned short* Wt_  = wt + (size_t)(l * 7 + 4 + t) * 16384;
    const unsigned short* Wx   = wext + (size_t)(l * 3 + t) * 8192;
    const unsigned short* Cadd = ho + hoff * 128;
    const float* g  = lng + t * 128;
    const float* bb = lnb + t * 128;
    int tid = threadIdx.x;
    long long row0 = (long long)lb * 128;
    // phase A: K 0..127
#pragma unroll
    for (int i = 0; i < 8; i++) {
        int idx = tid + i * 256;
        int m = idx >> 4, c = idx & 15;
        int sw = c ^ (m & 15);
        uint4 va = make_uint4(0u, 0u, 0u, 0u);
        long long gr = row0 + m;
        if (gr < M) va = *(const uint4*)&A[gr * 128 + c * 8];
        *(uint4*)&As[m * 128 + sw * 8] = va;
        uint4 wv = *(const uint4*)&Wt_[m * 128 + c * 8];
        *(uint4*)&Bs[m * 128 + sw * 8] = wv;
    }
    __syncthreads();
    int lane = tid & 63, w = tid >> 6;
    int q = lane >> 4, ml = lane & 15;
    v4f acc[2][8];
#pragma unroll
    for (int i = 0; i < 2; i++)
#pragma unroll
        for (int j = 0; j < 8; j++) acc[i][j] = (v4f){0.f, 0.f, 0.f, 0.f};
#pragma unroll
    for (int kc = 0; kc < 4; kc++) {
        int ch = (4 * kc + q) ^ ml;
        v8s af[2], bf[8];
#pragma unroll
        for (int i = 0; i < 2; i++) af[i] = *(const v8s*)&As[(32 * w + 16 * i + ml) * 128 + ch * 8];
#pragma unroll
        for (int j = 0; j < 8; j++) bf[j] = *(const v8s*)&Bs[(16 * j + ml) * 128 + ch * 8];
#pragma unroll
        for (int i = 0; i < 2; i++)
#pragma unroll
            for (int j = 0; j < 8; j++)
                acc[i][j] = __builtin_amdgcn_mfma_f32_16x16x32_bf16(af[i], bf[j], acc[i][j], 0, 0, 0);
    }
    __syncthreads();
    // phase B: K 128..191 (ext)
#pragma unroll
    for (int i = 0; i < 4; i++) {
        int idx = tid + i * 256;
        int m = idx >> 3, c = idx & 7;
        int sw = c ^ (m & 7);
        uint4 va = make_uint4(0u, 0u, 0u, 0u);
        long long gr = row0 + m;
        if (gr < M) va = *(const uint4*)&Ax[gr * 64 + c * 8];
        *(uint4*)&As[m * 64 + sw * 8] = va;
        uint4 wv = *(const uint4*)&Wx[m * 64 + c * 8];
        *(uint4*)&Bs[m * 64 + sw * 8] = wv;
    }
    __syncthreads();
#pragma unroll
    for (int kc = 0; kc < 2; kc++) {
        int ch = (4 * kc + q) ^ (ml & 7);
        v8s af[2], bf[8];
#pragma unroll
        for (int i = 0; i < 2; i++) af[i] = *(const v8s*)&As[(32 * w + 16 * i + ml) * 64 + ch * 8];
#pragma unroll
        for (int j = 0; j < 8; j++) bf[j] = *(const v8s*)&Bs[(16 * j + ml) * 64 + ch * 8];
#pragma unroll
        for (int i = 0; i < 2; i++)
#pragma unroll
            for (int j = 0; j < 8; j++)
                acc[i][j] = __builtin_amdgcn_mfma_f32_16x16x32_bf16(af[i], bf[j], acc[i][j], 0, 0, 0);
    }
    // epilogue: + Cadd (bf16), LayerNorm, store
    float gv[8], bv[8];
#pragma unroll
    for (int j = 0; j < 8; j++) { gv[j] = g[16 * j + ml]; bv[j] = bb[16 * j + ml]; }
    unsigned short* outb = ha + hoff * 128;
    float* outF = outf + hoff * 128;
#pragma unroll
    for (int i = 0; i < 2; i++) {
#pragma unroll
        for (int r = 0; r < 4; r++) {
            long long row = row0 + 32 * w + 16 * i + q * 4 + r;
            bool valid = row < M;
            float s = 0.f, s2 = 0.f;
#pragma unroll
            for (int j = 0; j < 8; j++) {
                float v = acc[i][j][r];
                if (valid) v += bf2f(Cadd[row * 128 + 16 * j + ml]);
                acc[i][j][r] = v;
                s += v; s2 += v * v;
            }
#pragma unroll
            for (int msk = 1; msk < 16; msk <<= 1) {
                s  += __shfl_xor(s,  msk);
                s2 += __shfl_xor(s2, msk);
            }
            float mean = s * 0.0078125f;
            float var  = s2 * 0.0078125f - mean * mean;
            float rs = rsqrtf(var + 1e-5f);
            if (valid) {
#pragma unroll
                for (int j = 0; j < 8; j++) {
                    float v = (acc[i][j][r] - mean) * rs * gv[j] + bv[j];
                    if (l == 0) outb[row * 128 + 16 * j + ml] = f2bf(v);
                    else        outF[row * 128 + 16 * j + ml] = v;
                }
            }
        }
    }
}

__global__ void fill_dn(float* __restrict__ of, const float* __restrict__ lnb3) {
    long long i4 = ((long long)blockIdx.x * 256 + threadIdx.x) * 4;
    if (i4 >= 12800000ll) return;
    int c = (int)(i4 & 127);
    *(float4*)&of[i4] = make_float4(lnb3[c], lnb3[c + 1], lnb3[c + 2], lnb3[c + 3]);
}

// ---------------- host launch ----------------
extern "C" void kernel_launch(void* const* d_in, const int* in_sizes, int n_in,
                              void* d_out, int out_size, void* d_ws, size_t ws_size,
                              hipStream_t stream) {
    if (ws_size < WS_NEEDED) return;

    const float* h0[4] = {(const float*)d_in[0], (const float*)d_in[1],
                          (const float*)d_in[2], (const float*)d_in[3]};
    const float* ftp[4] = {(const float*)d_in[4], (const float*)d_in[5],
                           (const float*)d_in[6], (const float*)d_in[7]};
    const float* convW = (const float*)d_in[8];
    const float* convb = (const float*)d_in[9];
    const float* emlpW = (const float*)d_in[10];
    const float* emlpb = (const float*)d_in[11];
    const float* lng   = (const float*)d_in[12];
    const float* lnb   = (const float*)d_in[13];
    const int* srcp[4] = {(const int*)d_in[14], (const int*)d_in[16],
                          (const int*)d_in[18], (const int*)d_in[20]};
    const int* dstp[4] = {(const int*)d_in[15], (const int*)d_in[17],
                          (const int*)d_in[19], (const int*)d_in[21]};
    char* ws = (char*)d_ws;
    float* out = (float*)d_out;

    int* deg = (int*)(ws + DEG_B);
    int* off = (int*)(ws + OFF_B);
    int* cur = (int*)(ws + CUR_B);
    int* csr_src = (int*)(ws + CSRS_B);
    float* fts = (float*)(ws + FTS_B);
    int* bsum = (int*)(ws + BSUM_B);
    int* bpre = (int*)(ws + BPRE_B);
    unsigned short* wt   = (unsigned short*)(ws + WT_B);
    unsigned short* wext = (unsigned short*)(ws + WEXT_B);
    float* vrow = (float*)(ws + VROW_B);
    unsigned short* aext = (unsigned short*)(ws + AEXT_B);
    unsigned short* ha = (unsigned short*)(ws + HA_B);
    unsigned short* za = (unsigned short*)(ws + ZA_B);
    unsigned short* ho = (unsigned short*)(ws + HO_B);

    hipMemsetAsync(deg, 0, 4 * S_I * sizeof(int), stream);
    hipMemsetAsync(fts, 0, 222000ull * 16 * sizeof(float), stream);

    IPtr4 dsts; for (int e = 0; e < 4; e++) dsts.p[e] = dstp[e];
    FPtr4 ftq;  for (int e = 0; e < 4; e++) ftq.p[e] = ftp[e];
    hist_ft<<<93750, 256, 0, stream>>>(dsts, ftq, deg, fts);

    scan_p1<<<218, 256, 0, stream>>>(deg, bsum);
    scan_p2<<<1, 256, 0, stream>>>(bsum, bpre, off);
    scan_p3<<<218, 256, 0, stream>>>(deg, bpre, off, cur);
    IPtr8 sd;
    for (int e = 0; e < 4; e++) { sd.s[e] = srcp[e]; sd.d[e] = dstp[e]; }
    fillcsr_all<<<5860, 256, 0, stream>>>(sd, cur, csr_src);

    const_build<<<1089, 256, 0, stream>>>(convW, emlpW, emlpb, convb, lnb, wt, wext, vrow);
    FPtr4 hq; for (int t = 0; t < 4; t++) hq.p[t] = h0[t];
    h0cvt<<<27750, 256, 0, stream>>>(hq, ha);
    aext_build<<<30500, 256, 0, stream>>>(off, fts, aext);

    for (int l = 0; l < 2; l++) {
        zgemm<<<(l == 0) ? 1737 : 955, 256, 0, stream>>>(l, ha, wt, za);
        pull_all<<<30500, 256, 0, stream>>>(l, off, csr_src, za, vrow, ho);
        selfgemm<<<955, 256, 0, stream>>>(l, ha, wt, wext, aext, ho, out, lng, lnb);
    }
    fill_dn<<<12500, 256, 0, stream>>>(out + 122000ll * 128, lnb + 384);
}